// Round 2
// 12530.599 us; speedup vs baseline: 2.0957x; 2.0957x over previous
//
#include <hip/hip_runtime.h>
#include <hip/hip_bf16.h>

#define EPSN 1e-5f

typedef __hip_bfloat16 bf16;
typedef __attribute__((ext_vector_type(8))) short bf16x8;
typedef __attribute__((ext_vector_type(4))) float f32x4;

__device__ __forceinline__ float b2f(bf16 v) { return __bfloat162float(v); }
__device__ __forceinline__ bf16 f2b(float v) { return __float2bfloat16(v); }
__device__ __forceinline__ unsigned short f2bu(float v) {
  bf16 h = __float2bfloat16(v);
  return *reinterpret_cast<unsigned short*>(&h);
}
__device__ __forceinline__ void stv(bf16* p, size_t i, float v) { p[i] = f2b(v); }
__device__ __forceinline__ void stv(float* p, size_t i, float v) { p[i] = v; }

// ---------------- zero the stats scratch (atomicAdd target) -----------------
__global__ void zero_stats_kernel(float* __restrict__ stats) {
  for (int k = threadIdx.x; k < 2048; k += 256) stats[k] = 0.f;
}

// ------- weight convert: [Co][Ci][3][3] fp32 -> [tap][co][ci] bf16 hi+lo ----
// hi plane at wb[0..4718592), lo plane at wb[4718592..9437184)
__global__ __launch_bounds__(256) void convert_w_kernel(
    const float* __restrict__ rw1, const float* __restrict__ rw2,
    unsigned short* __restrict__ wb) {
  int i = blockIdx.x * 256 + threadIdx.x;  // < 8*9*65536 = 4718592
  if (i >= 4718592) return;
  int conv = i / 589824;
  int rem = i % 589824;
  int tap = rem / 65536;
  int cc = rem % 65536;  // co*256+ci
  const float* src = ((conv & 1) ? rw2 : rw1) + (size_t)(conv >> 1) * 589824;
  float v = src[(size_t)cc * 9 + tap];
  bf16 h = __float2bfloat16(v);
  float fh = __bfloat162float(h);
  wb[i] = *reinterpret_cast<unsigned short*>(&h);
  bf16 l = __float2bfloat16(v - fh);
  wb[4718592 + i] = *reinterpret_cast<unsigned short*>(&l);
}

// ---------------- 3x3 s1 p1 conv via MFMA (bf16x3), Ci=Co=256, H=W=128 ------
// Block: 4 waves, tile 128co x 128px (one row). Wave tile 64x64.
// W*X ~= Wh*Xh + Wh*Xl + Wl*Xh  (fp32-accurate; drops only Wl*Xl ~ 2^-18)
// LDS: X hi+lo 3-row halo (49.9KB) + A hi+lo one tap (16KB) = 66.3KB -> 2 blk/CU
__device__ __forceinline__ int swz3(int idx) {
  return (idx & 3) ^ ((idx >> 2) & 1);
}

__global__ __launch_bounds__(256) void conv3x3s1_mfma(
    const float* __restrict__ x, const unsigned short* __restrict__ wh,
    const unsigned short* __restrict__ wl, const float* __restrict__ bias,
    float* __restrict__ y) {
  const int H = 128, W = 128;
  int r = blockIdx.x;    // output row
  int cog = blockIdx.y;  // 0..1 (128 co each)
  int n = blockIdx.z;
  int tid = threadIdx.x;
  int wv = tid >> 6, lane = tid & 63;
  int wco = (wv >> 1) * 64, wpx = (wv & 1) * 64;
  int l15 = lane & 15, l4 = lane >> 4;

  // Xh/Xl: [row 3][col 130][ci 32] bf16, 16B ci-slots swizzled by swz3(col)
  // Ah/Al: [co 128][ci 32] bf16 (one tap), 16B ci-slots swizzled by swz3(co)
  __shared__ __align__(16) unsigned short Xh[3 * 130 * 32];
  __shared__ __align__(16) unsigned short Xl[3 * 130 * 32];
  __shared__ __align__(16) unsigned short Ah[128 * 32];
  __shared__ __align__(16) unsigned short Al[128 * 32];

  f32x4 acc[4][4];
#pragma unroll
  for (int m = 0; m < 4; ++m)
#pragma unroll
    for (int nf = 0; nf < 4; ++nf) acc[m][nf] = (f32x4){0.f, 0.f, 0.f, 0.f};

  const float* xn0 = x + (size_t)n * 256 * H * W;

  for (int cb = 0; cb < 8; ++cb) {
    int ci0 = cb * 32;
    // ---- stage input slice hi+lo: rows r-1..r+1, cols -1..128 ----
    {
      const float* xn = xn0 + (size_t)ci0 * H * W;
      for (int t = tid; t < 1560; t += 256) {
        int q = t & 3;
        int cr = t >> 2;     // 0..389
        int col = cr % 130;  // 0..129
        int row = cr / 130;  // 0..2
        int gr = r + row - 1;
        int gc = col - 1;
        bool ok = (gr >= 0) && (gr < H) && (gc >= 0) && (gc < W);
        uint4 ph = {0, 0, 0, 0};
        uint4 pl = {0, 0, 0, 0};
        if (ok) {
          const float* xp =
              xn + (size_t)(q * 8) * (H * W) + (size_t)gr * W + gc;
          unsigned short vh[8], vl[8];
#pragma unroll
          for (int e = 0; e < 8; ++e) {
            float v = xp[(size_t)e * H * W];
            bf16 hb = __float2bfloat16(v);
            float fh = __bfloat162float(hb);
            bf16 lb = __float2bfloat16(v - fh);
            vh[e] = *reinterpret_cast<unsigned short*>(&hb);
            vl[e] = *reinterpret_cast<unsigned short*>(&lb);
          }
          ph.x = (unsigned)vh[0] | ((unsigned)vh[1] << 16);
          ph.y = (unsigned)vh[2] | ((unsigned)vh[3] << 16);
          ph.z = (unsigned)vh[4] | ((unsigned)vh[5] << 16);
          ph.w = (unsigned)vh[6] | ((unsigned)vh[7] << 16);
          pl.x = (unsigned)vl[0] | ((unsigned)vl[1] << 16);
          pl.y = (unsigned)vl[2] | ((unsigned)vl[3] << 16);
          pl.z = (unsigned)vl[4] | ((unsigned)vl[5] << 16);
          pl.w = (unsigned)vl[6] | ((unsigned)vl[7] << 16);
        }
        int slot = (cr * 4 + (q ^ swz3(col))) * 8;
        *(uint4*)(&Xh[slot]) = ph;
        *(uint4*)(&Xl[slot]) = pl;
      }
    }
    // ---- 9 taps; stage one tap's A (hi+lo), 48 MFMAs each ----
    for (int tap = 0; tap < 9; ++tap) {
      for (int t = tid; t < 1024; t += 256) {
        int half = t >> 9;
        int rem = t & 511;
        int q = rem & 3;
        int co = rem >> 2;
        const unsigned short* wsrc =
            (half ? wl : wh) +
            ((size_t)tap * 256 + cog * 128 + co) * 256 + ci0 + q * 8;
        uint4 pk = *(const uint4*)wsrc;
        int slot = (co * 4 + (q ^ swz3(co))) * 8;
        *(uint4*)((half ? Al : Ah) + slot) = pk;
      }
      __syncthreads();
      int ky = tap / 3;
      int kx = tap - ky * 3;
      bf16x8 ahf[4], alf[4], bhf[4], blf[4];
#pragma unroll
      for (int m = 0; m < 4; ++m) {
        int co = wco + m * 16 + l15;
        int slot = (co * 4 + (l4 ^ swz3(co))) * 8;
        ahf[m] = *(const bf16x8*)(&Ah[slot]);
        alf[m] = *(const bf16x8*)(&Al[slot]);
      }
#pragma unroll
      for (int nf = 0; nf < 4; ++nf) {
        int col = wpx + nf * 16 + l15 + kx;  // lds col = px + kx
        int slot = ((ky * 130 + col) * 4 + (l4 ^ swz3(col))) * 8;
        bhf[nf] = *(const bf16x8*)(&Xh[slot]);
        blf[nf] = *(const bf16x8*)(&Xl[slot]);
      }
#pragma unroll
      for (int m = 0; m < 4; ++m)
#pragma unroll
        for (int nf = 0; nf < 4; ++nf) {
          acc[m][nf] = __builtin_amdgcn_mfma_f32_16x16x32_bf16(
              ahf[m], bhf[nf], acc[m][nf], 0, 0, 0);
          acc[m][nf] = __builtin_amdgcn_mfma_f32_16x16x32_bf16(
              ahf[m], blf[nf], acc[m][nf], 0, 0, 0);
          acc[m][nf] = __builtin_amdgcn_mfma_f32_16x16x32_bf16(
              alf[m], bhf[nf], acc[m][nf], 0, 0, 0);
        }
      __syncthreads();  // protect Ah/Al (next tap) and Xh/Xl (next cb)
    }
  }
  // ---- epilogue: bias + store ----
#pragma unroll
  for (int m = 0; m < 4; ++m) {
    int cob = cog * 128 + wco + m * 16 + l4 * 4;
#pragma unroll
    for (int reg = 0; reg < 4; ++reg) {
      float bv = bias[cob + reg];
      float* yr =
          y + (((size_t)(n * 256 + cob + reg) * H) + r) * W + wpx + l15;
#pragma unroll
      for (int nf = 0; nf < 4; ++nf) yr[nf * 16] = acc[m][nf][reg] + bv;
    }
  }
}

// ---------------- 7x7 conv p3, register-tiled: 4 px x CO_T co ---------------
// MODE 0: conv -> per-(n,co) sum/sumsq atomicAdd into stats (no activation out)
// MODE 1: conv -> AdaLIN scale/shift from stats + relu -> y (stored as n=0)
// MODE 2: conv -> tanh -> y (full n indexing)
template <int MODE, int CO_T, typename Tin>
__global__ __launch_bounds__(256) void conv7_tile(
    const Tin* __restrict__ x, const float* __restrict__ w,
    const float* __restrict__ bias, float* __restrict__ stats,
    float* __restrict__ y, int Ci, int H, int W, int n_ov) {
  __shared__ float ss[256], qq[256];
  int cog = blockIdx.y;
  int Co = gridDim.y * CO_T;
  int n = (MODE == 1) ? n_ov : blockIdx.z;
  int CG = W >> 2;
  int rpb = 256 / CG;
  int tid = threadIdx.x;
  int r = blockIdx.x * rpb + tid / CG;
  int c0 = (tid % CG) * 4;
  const Tin* xb = x + (size_t)n * Ci * H * W;
  int cr[7];
  float mr[7];
#pragma unroll
  for (int i = 0; i < 7; ++i) {
    int rr = r - 3 + i;
    mr[i] = (rr >= 0 && rr < H) ? 1.f : 0.f;
    cr[i] = min(max(rr, 0), H - 1);
  }
  int cc[10];
  float mc[10];
#pragma unroll
  for (int k = 0; k < 10; ++k) {
    int c = c0 - 3 + k;
    mc[k] = (c >= 0 && c < W) ? 1.f : 0.f;
    cc[k] = min(max(c, 0), W - 1);
  }
  float acc[CO_T][4];
#pragma unroll
  for (int j = 0; j < CO_T; ++j) {
    float b = bias[cog * CO_T + j];
#pragma unroll
    for (int p = 0; p < 4; ++p) acc[j][p] = b;
  }
  for (int ci = 0; ci < Ci; ++ci) {
    const Tin* xc = xb + (size_t)ci * H * W;
#pragma unroll
    for (int i = 0; i < 7; ++i) {
      const Tin* xr = xc + (size_t)cr[i] * W;
      float v[10];
#pragma unroll
      for (int k = 0; k < 10; ++k) v[k] = (float)xr[cc[k]] * (mr[i] * mc[k]);
#pragma unroll
      for (int j = 0; j < CO_T; ++j) {
        const float* wr =
            w + ((size_t)(cog * CO_T + j) * Ci + ci) * 49 + i * 7;
#pragma unroll
        for (int p = 0; p < 4; ++p) {
          acc[j][p] += v[p] * wr[0] + v[p + 1] * wr[1] + v[p + 2] * wr[2] +
                       v[p + 3] * wr[3] + v[p + 4] * wr[4] + v[p + 5] * wr[5] +
                       v[p + 6] * wr[6];
        }
      }
    }
  }
  if (MODE == 0) {
#pragma unroll
    for (int j = 0; j < CO_T; ++j) {
      float s = acc[j][0] + acc[j][1] + acc[j][2] + acc[j][3];
      float q = acc[j][0] * acc[j][0] + acc[j][1] * acc[j][1] +
                acc[j][2] * acc[j][2] + acc[j][3] * acc[j][3];
      ss[tid] = s;
      qq[tid] = q;
      __syncthreads();
      for (int off = 128; off > 0; off >>= 1) {
        if (tid < off) {
          ss[tid] += ss[tid + off];
          qq[tid] += qq[tid + off];
        }
        __syncthreads();
      }
      if (tid == 0) {
        atomicAdd(&stats[n * Co + cog * CO_T + j], ss[0]);
        atomicAdd(&stats[1024 + n * Co + cog * CO_T + j], qq[0]);
      }
      __syncthreads();
    }
  } else if (MODE == 1) {
#pragma unroll
    for (int j = 0; j < CO_T; ++j) {
      int co = cog * CO_T + j;
      float sc = stats[2048 + n * Co + co];
      float sh = stats[3072 + n * Co + co];
      float4 o;
      o.x = fmaxf(acc[j][0] * sc + sh, 0.f);
      o.y = fmaxf(acc[j][1] * sc + sh, 0.f);
      o.z = fmaxf(acc[j][2] * sc + sh, 0.f);
      o.w = fmaxf(acc[j][3] * sc + sh, 0.f);
      *(float4*)(y + ((size_t)co * H + r) * W + c0) = o;
    }
  } else {
#pragma unroll
    for (int j = 0; j < CO_T; ++j) {
      int co = cog * CO_T + j;
      float4 o;
      o.x = tanhf(acc[j][0]);
      o.y = tanhf(acc[j][1]);
      o.z = tanhf(acc[j][2]);
      o.w = tanhf(acc[j][3]);
      *(float4*)(y + ((size_t)(n * Co + co) * H + r) * W + c0) = o;
    }
  }
}

// ---------------- 3x3 s2 p1 conv, tiled 4 px x 4 co, fp32 -------------------
// launched with z=1 and pre-offset x/y (e2 per-batch) or z=4 (e3).
__global__ __launch_bounds__(256) void conv3x3s2_tile(
    const float* __restrict__ x, const float* __restrict__ w,
    const float* __restrict__ bias, float* __restrict__ y, int Ci, int Hi,
    int Wi) {
  int Ho = Hi >> 1, Wo = Wi >> 1;
  int cog = blockIdx.y;
  int Co = gridDim.y * 4;
  int n = blockIdx.z;
  int CG = Wo >> 2;
  int rpb = 256 / CG;
  int tid = threadIdx.x;
  int r = blockIdx.x * rpb + tid / CG;
  int c0 = (tid % CG) * 4;
  const float* xb = x + (size_t)n * Ci * Hi * Wi;
  int ir0 = 2 * r - 1;
  float mr0 = (ir0 >= 0) ? 1.f : 0.f;
  int cr0 = max(ir0, 0);
  int icl = 2 * c0 - 1;
  float mcl = (icl >= 0) ? 1.f : 0.f;
  int ccl = max(icl, 0);
  float acc[4][4];
#pragma unroll
  for (int j = 0; j < 4; ++j) {
    float b = bias[cog * 4 + j];
#pragma unroll
    for (int p = 0; p < 4; ++p) acc[j][p] = b;
  }
  for (int ci = 0; ci < Ci; ++ci) {
    const float* xc = xb + (size_t)ci * Hi * Wi;
    float v[3][9];
#pragma unroll
    for (int i = 0; i < 3; ++i) {
      int rr = (i == 0) ? cr0 : (2 * r - 1 + i);
      float mi = (i == 0) ? mr0 : 1.f;
      const float* xr = xc + (size_t)rr * Wi;
      float4 a = *(const float4*)(xr + 2 * c0);
      float4 b4 = *(const float4*)(xr + 2 * c0 + 4);
      v[i][0] = xr[ccl] * (mcl * mi);
      v[i][1] = a.x * mi;
      v[i][2] = a.y * mi;
      v[i][3] = a.z * mi;
      v[i][4] = a.w * mi;
      v[i][5] = b4.x * mi;
      v[i][6] = b4.y * mi;
      v[i][7] = b4.z * mi;
      v[i][8] = b4.w * mi;
    }
#pragma unroll
    for (int j = 0; j < 4; ++j) {
      const float* wc = w + ((size_t)(cog * 4 + j) * Ci + ci) * 9;
#pragma unroll
      for (int p = 0; p < 4; ++p) {
        acc[j][p] += v[0][2 * p] * wc[0] + v[0][2 * p + 1] * wc[1] +
                     v[0][2 * p + 2] * wc[2] + v[1][2 * p] * wc[3] +
                     v[1][2 * p + 1] * wc[4] + v[1][2 * p + 2] * wc[5] +
                     v[2][2 * p] * wc[6] + v[2][2 * p + 1] * wc[7] +
                     v[2][2 * p + 2] * wc[8];
      }
    }
  }
#pragma unroll
  for (int j = 0; j < 4; ++j) {
    float4 o = {acc[j][0], acc[j][1], acc[j][2], acc[j][3]};
    *(float4*)(y + ((size_t)(n * Co + cog * 4 + j) * Ho + r) * Wo + c0) = o;
  }
}

// ---------------- 1x1 conv, tiled 4 px x 4 co, fp32 -------------------------
__global__ __launch_bounds__(256) void conv1x1_tile(
    const float* __restrict__ x, const float* __restrict__ w,
    const float* __restrict__ bias, float* __restrict__ y, int Ci, int HW) {
  int cog = blockIdx.y;
  int Co = gridDim.y * 4;
  int n = blockIdx.z;
  int p0 = (blockIdx.x * 256 + threadIdx.x) * 4;
  const float* xb = x + (size_t)n * Ci * HW + p0;
  float acc[4][4];
#pragma unroll
  for (int j = 0; j < 4; ++j) {
    float b = bias[cog * 4 + j];
#pragma unroll
    for (int p = 0; p < 4; ++p) acc[j][p] = b;
  }
  for (int ci = 0; ci < Ci; ++ci) {
    float4 xv = *(const float4*)(xb + (size_t)ci * HW);
#pragma unroll
    for (int j = 0; j < 4; ++j) {
      float wv = w[(size_t)(cog * 4 + j) * Ci + ci];
      acc[j][0] += xv.x * wv;
      acc[j][1] += xv.y * wv;
      acc[j][2] += xv.z * wv;
      acc[j][3] += xv.w * wv;
    }
  }
#pragma unroll
  for (int j = 0; j < 4; ++j) {
    float4 o = {acc[j][0], acc[j][1], acc[j][2], acc[j][3]};
    *(float4*)(y + (size_t)(n * Co + cog * 4 + j) * HW + p0) = o;
  }
}

// ---------------- ConvTranspose2d k3 s2 p1 op1, tiled 2x2 quad x 4 co -------
// weights [Ci,Co,3,3]; output quad (2y,2x..2y+1,2x+1) from input patch (y,x)
template <typename Tin, typename Tout>
__global__ __launch_bounds__(256) void convt3x3_tile(
    const Tin* __restrict__ x, const float* __restrict__ w,
    const float* __restrict__ bias, Tout* __restrict__ y, int Ci, int Hi,
    int Wi) {
  int Ho = Hi * 2, Wo = Wi * 2;
  int cog = blockIdx.y;
  int Co = gridDim.y * 4;
  int n = blockIdx.z;
  int q = blockIdx.x * 256 + threadIdx.x;
  int yq = q / Wi, xq = q % Wi;
  const Tin* xb = x + (size_t)n * Ci * Hi * Wi;
  float mx = (xq + 1 < Wi) ? 1.f : 0.f;
  int x1 = min(xq + 1, Wi - 1);
  float my = (yq + 1 < Hi) ? 1.f : 0.f;
  int y1 = min(yq + 1, Hi - 1);
  float mxy = mx * my;
  float acc[4][4];
#pragma unroll
  for (int j = 0; j < 4; ++j) {
    float b = bias[cog * 4 + j];
#pragma unroll
    for (int p = 0; p < 4; ++p) acc[j][p] = b;
  }
  for (int ci = 0; ci < Ci; ++ci) {
    const Tin* xc = xb + (size_t)ci * Hi * Wi;
    float a = (float)xc[(size_t)yq * Wi + xq];
    float bv = (float)xc[(size_t)yq * Wi + x1] * mx;
    float c = (float)xc[(size_t)y1 * Wi + xq] * my;
    float d = (float)xc[(size_t)y1 * Wi + x1] * mxy;
#pragma unroll
    for (int j = 0; j < 4; ++j) {
      const float* wc = w + ((size_t)ci * Co + cog * 4 + j) * 9;
      acc[j][0] += a * wc[4];
      acc[j][1] += bv * wc[3] + a * wc[5];
      acc[j][2] += c * wc[1] + a * wc[7];
      acc[j][3] += d * wc[0] + c * wc[2] + bv * wc[6] + a * wc[8];
    }
  }
#pragma unroll
  for (int j = 0; j < 4; ++j) {
    size_t base = ((size_t)(n * Co + cog * 4 + j) * Ho + 2 * yq) * Wo + 2 * xq;
    stv(y, base, acc[j][0]);
    stv(y, base + 1, acc[j][1]);
    stv(y, base + Wo, acc[j][2]);
    stv(y, base + Wo + 1, acc[j][3]);
  }
}

// ---------------- per-(n,c) sum / sumsq reduction ---------------------------
template <typename Tin>
__global__ __launch_bounds__(256) void reduce_nc_kernel(
    const Tin* __restrict__ x, float* __restrict__ stats, int HW) {
  int b = blockIdx.x;
  const Tin* p = x + (size_t)b * HW;
  float s = 0.f, q = 0.f;
  for (int i = threadIdx.x; i < HW; i += 256) {
    float v = (float)p[i];
    s += v;
    q += v * v;
  }
  __shared__ float ss[256], qq[256];
  ss[threadIdx.x] = s;
  qq[threadIdx.x] = q;
  __syncthreads();
  for (int off = 128; off > 0; off >>= 1) {
    if (threadIdx.x < off) {
      ss[threadIdx.x] += ss[threadIdx.x + off];
      qq[threadIdx.x] += qq[threadIdx.x + off];
    }
    __syncthreads();
  }
  if (threadIdx.x == 0) {
    stats[b] = ss[0];
    stats[1024 + b] = qq[0];
  }
}

// ---------------- AdaLIN coefficients ---------------------------------------
__global__ void adalin_coef_kernel(float* __restrict__ stats,
                                   const float* __restrict__ rho,
                                   const float* __restrict__ gam,
                                   const float* __restrict__ bet, int N, int C,
                                   float invHW) {
  int i = blockIdx.x * blockDim.x + threadIdx.x;
  if (i >= N * C) return;
  int c = i % C;
  const float* sums = stats;
  const float* sqs = stats + 1024;
  float im = sums[i] * invHW;
  float iv = sqs[i] * invHW - im * im;
  float lsum = 0.f, lsq = 0.f;
  for (int n = 0; n < N; ++n) {
    lsum += sums[n * C + c];
    lsq += sqs[n * C + c];
  }
  float lm = lsum * invHW / N;
  float lv = lsq * invHW / N - lm * lm;
  float r = rho[c];
  float mean = r * im + (1.f - r) * lm;
  float var = fmaxf(r * iv + (1.f - r) * lv, 0.f);
  float sc = gam[c] / sqrtf(var + EPSN);
  stats[2048 + i] = sc;
  stats[3072 + i] = bet[c] - mean * sc;
}

// ---------------- InstanceNorm coefficients ---------------------------------
__global__ void inorm_coef_kernel(float* __restrict__ stats, int NC,
                                  float invHW) {
  int i = blockIdx.x * blockDim.x + threadIdx.x;
  if (i >= NC) return;
  float im = stats[i] * invHW;
  float iv = fmaxf(stats[1024 + i] * invHW - im * im, 0.f);
  float sc = 1.f / sqrtf(iv + EPSN);
  stats[2048 + i] = sc;
  stats[3072 + i] = -im * sc;
}

// ---------------- x = (relu?)(x*scale[nc] + shift[nc])  (in-place) ----------
template <typename T>
__global__ __launch_bounds__(256) void scale_shift_kernel(
    T* __restrict__ x, const float* __restrict__ stats, int HW, size_t total,
    int relu) {
  size_t i = (size_t)blockIdx.x * 256 + threadIdx.x;
  if (i >= total) return;
  int nc = (int)(i / (size_t)HW);
  float v = (float)x[i] * stats[2048 + nc] + stats[3072 + nc];
  if (relu) v = fmaxf(v, 0.f);
  stv(x, i, v);
}

// ---------------- dst = relu(dst + a)  (fp32) -------------------------------
__global__ __launch_bounds__(256) void add_relu_kernel(
    float* __restrict__ dst, const float* __restrict__ a, size_t total) {
  size_t i = (size_t)blockIdx.x * 256 + threadIdx.x;
  if (i >= total) return;
  dst[i] = fmaxf(dst[i] + a[i], 0.f);
}

// ---------------- windowed attention (all fp32) -----------------------------
__global__ __launch_bounds__(256) void win_attn_kernel(
    const float* __restrict__ f, const float* __restrict__ g,
    const float* __restrict__ h, float* __restrict__ out) {
  const int H = 128;
  int j = blockIdx.x;
  int i = blockIdx.y;
  int b = blockIdx.z;
  __shared__ float fs[32 * 64];
  __shared__ float gs[32 * 64];
  __shared__ float att[16 * 64];
  int t = threadIdx.x;
  for (int idx = t; idx < 32 * 64; idx += 256) {
    int c = idx >> 6, k = idx & 63;
    int hr = i * 4 + (k >> 3), wc = j * 4 + (k & 7);
    float fv = 0.f, gv = 0.f;
    if (hr < H && wc < H) {
      size_t o = ((size_t)(b * 32 + c) * H + hr) * H + wc;
      fv = f[o];
      gv = g[o];
    }
    fs[idx] = fv;
    gs[idx] = gv;
  }
  __syncthreads();
  for (int idx = t; idx < 1024; idx += 256) {
    int q = idx >> 6, k = idx & 63;
    int qi = (q >> 2) * 8 + (q & 3);
    int hr = i * 4 + (k >> 3), wc = j * 4 + (k & 7);
    float s;
    if (hr < H && wc < H) {
      s = 0.f;
      for (int c = 0; c < 32; ++c) s += fs[c * 64 + qi] * gs[c * 64 + k];
    } else {
      s = -1e30f;
    }
    att[idx] = s;
  }
  __syncthreads();
  if (t < 16) {
    float m = -1e30f;
    for (int k = 0; k < 64; ++k) m = fmaxf(m, att[t * 64 + k]);
    float d = 0.f;
    for (int k = 0; k < 64; ++k) {
      float e = expf(att[t * 64 + k] - m);
      att[t * 64 + k] = e;
      d += e;
    }
    float inv = 1.f / d;
    for (int k = 0; k < 64; ++k) att[t * 64 + k] *= inv;
  }
  __syncthreads();
  int c = t;
  float accs[16];
  for (int q = 0; q < 16; ++q) accs[q] = 0.f;
  const float* hb = h + (size_t)(b * 256 + c) * H * H;
  for (int k = 0; k < 64; ++k) {
    int hr = i * 4 + (k >> 3), wc = j * 4 + (k & 7);
    if (hr >= H || wc >= H) continue;
    float hv = hb[hr * H + wc];
    for (int q = 0; q < 16; ++q) accs[q] += hv * att[q * 64 + k];
  }
  for (int q = 0; q < 16; ++q) {
    int oh = i * 4 + (q >> 2), ow = j * 4 + (q & 3);
    out[((size_t)(b * 256 + c) * H + oh) * H + ow] = accs[q];
  }
}

// ============================================================================
extern "C" void kernel_launch(void* const* d_in, const int* in_sizes, int n_in,
                              void* d_out, int out_size, void* d_ws,
                              size_t ws_size, hipStream_t stream) {
  const float* x = (const float*)d_in[0];
  const float* w_e1 = (const float*)d_in[1];
  const float* b_e1 = (const float*)d_in[2];
  const float* rho1 = (const float*)d_in[3];
  const float* gam1 = (const float*)d_in[4];
  const float* bet1 = (const float*)d_in[5];
  const float* w_e2 = (const float*)d_in[6];
  const float* b_e2 = (const float*)d_in[7];
  const float* rho2 = (const float*)d_in[8];
  const float* gam2 = (const float*)d_in[9];
  const float* bet2 = (const float*)d_in[10];
  const float* w_e3 = (const float*)d_in[11];
  const float* b_e3 = (const float*)d_in[12];
  const float* rho3 = (const float*)d_in[13];
  const float* gam3 = (const float*)d_in[14];
  const float* bet3 = (const float*)d_in[15];
  const float* rw1 = (const float*)d_in[16];
  const float* rb1 = (const float*)d_in[17];
  const float* rw2 = (const float*)d_in[18];
  const float* rb2 = (const float*)d_in[19];
  const float* w_f = (const float*)d_in[20];
  const float* b_f = (const float*)d_in[21];
  const float* w_g = (const float*)d_in[22];
  const float* b_g = (const float*)d_in[23];
  const float* w_h = (const float*)d_in[24];
  const float* b_h = (const float*)d_in[25];
  const float* w_d1 = (const float*)d_in[26];
  const float* b_d1 = (const float*)d_in[27];
  const float* rho4 = (const float*)d_in[28];
  const float* gam4 = (const float*)d_in[29];
  const float* bet4 = (const float*)d_in[30];
  const float* w_d2 = (const float*)d_in[31];
  const float* b_d2 = (const float*)d_in[32];
  const float* rho5 = (const float*)d_in[33];
  const float* gam5 = (const float*)d_in[34];
  const float* bet5 = (const float*)d_in[35];
  const float* w_d3 = (const float*)d_in[36];
  const float* b_d3 = (const float*)d_in[37];

  // ws layout (192 MiB, validated round 6):
  // [0,64):   A64 (e1-norm batch) -> Cc fp32 -> A2 bf16 [0,128) (d2 out)
  // [64,192): Bb fp32 (e2) -> D[64,128)+E[128,192) fp32, F1/F2 in [64,80)
  //           -> Bb2 bf16 [128,192) (d1 out)
  char* wsb = (char*)d_ws;
  float* A64 = (float*)wsb;
  float* Cc = (float*)wsb;
  float* Bb = (float*)(wsb + 67108864);
  float* D = (float*)(wsb + 67108864);
  float* E = (float*)(wsb + 134217728);
  float* F1 = (float*)(wsb + 67108864);
  float* F2 = (float*)(wsb + 75497472);
  bf16* Bb2 = (bf16*)(wsb + 134217728);
  bf16* A2 = (bf16*)wsb;

  float* out_img = (float*)d_out;
  float* out_attn = out_img + 3145728;
  // 16 KiB stats scratch at head of img region; fully overwritten by head conv
  float* stats = (float*)d_out;
  // bf16 hi+lo residual weights scratch: lives in the (not yet written)
  // out_attn region; fully consumed before win_attn_kernel writes out_attn.
  // hi plane 9.0MiB + lo plane 9.0MiB = 18MiB < 64MiB region.
  unsigned short* wbres = (unsigned short*)((char*)d_out + 12582912);

  dim3 blk(256);

  // ---- convert residual weights to bf16 hi+lo [tap][co][ci] (once) ----
  convert_w_kernel<<<18432, blk, 0, stream>>>(rw1, rw2, wbres);

  // ---- e1 pass 1: 7x7 conv + stats (no store) ----
  zero_stats_kernel<<<1, 256, 0, stream>>>(stats);
  conv7_tile<0, 4, float><<<dim3(256, 16, 4), blk, 0, stream>>>(
      x, w_e1, b_e1, stats, nullptr, 3, 512, 512, 0);
  adalin_coef_kernel<<<1, 256, 0, stream>>>(stats, rho1, gam1, bet1, 4, 64,
                                            1.f / 262144.f);
  // ---- e1 pass 2 (recompute+norm+relu, per batch) fused with e2 conv ----
  for (int n = 0; n < 4; ++n) {
    conv7_tile<1, 4, float><<<dim3(256, 16, 1), blk, 0, stream>>>(
        x, w_e1, b_e1, stats, A64, 3, 512, 512, n);
    conv3x3s2_tile<<<dim3(64, 32, 1), blk, 0, stream>>>(
        A64, w_e2, b_e2, Bb + (size_t)n * 128 * 65536, 64, 512, 512);
  }
  // ---- e2 AdaLIN + relu ----
  reduce_nc_kernel<float><<<512, blk, 0, stream>>>(Bb, stats, 65536);
  adalin_coef_kernel<<<2, 256, 0, stream>>>(stats, rho2, gam2, bet2, 4, 128,
                                            1.f / 65536.f);
  scale_shift_kernel<float><<<131072, blk, 0, stream>>>(Bb, stats, 65536,
                                                        (size_t)33554432, 1);
  // ---- e3: 3x3 s2, AdaLIN, relu ----
  conv3x3s2_tile<<<dim3(16, 64, 4), blk, 0, stream>>>(Bb, w_e3, b_e3, Cc, 128,
                                                      256, 256);
  reduce_nc_kernel<float><<<1024, blk, 0, stream>>>(Cc, stats, 16384);
  adalin_coef_kernel<<<4, 256, 0, stream>>>(stats, rho3, gam3, bet3, 4, 256,
                                            1.f / 16384.f);
  scale_shift_kernel<float><<<65536, blk, 0, stream>>>(Cc, stats, 16384,
                                                       (size_t)16777216, 1);
  // ---- 4 residual blocks (bf16x3 MFMA convs) ----
  for (int r = 0; r < 4; ++r) {
    const float* rb1p = rb1 + (size_t)r * 256;
    const float* rb2p = rb2 + (size_t)r * 256;
    const unsigned short* w1h = wbres + (size_t)(r * 2) * 589824;
    const unsigned short* w1l = w1h + 4718592;
    const unsigned short* w2h = wbres + (size_t)(r * 2 + 1) * 589824;
    const unsigned short* w2l = w2h + 4718592;
    conv3x3s1_mfma<<<dim3(128, 2, 4), blk, 0, stream>>>(Cc, w1h, w1l, rb1p, D);
    reduce_nc_kernel<float><<<1024, blk, 0, stream>>>(D, stats, 16384);
    inorm_coef_kernel<<<4, 256, 0, stream>>>(stats, 1024, 1.f / 16384.f);
    scale_shift_kernel<float><<<65536, blk, 0, stream>>>(D, stats, 16384,
                                                         (size_t)16777216, 1);
    conv3x3s1_mfma<<<dim3(128, 2, 4), blk, 0, stream>>>(D, w2h, w2l, rb2p, E);
    reduce_nc_kernel<float><<<1024, blk, 0, stream>>>(E, stats, 16384);
    inorm_coef_kernel<<<4, 256, 0, stream>>>(stats, 1024, 1.f / 16384.f);
    scale_shift_kernel<float><<<65536, blk, 0, stream>>>(E, stats, 16384,
                                                         (size_t)16777216, 0);
    add_relu_kernel<<<65536, blk, 0, stream>>>(Cc, E, (size_t)16777216);
  }
  // ---- attention: 1x1 convs f/g/h + windowed attention ----
  conv1x1_tile<<<dim3(16, 8, 4), blk, 0, stream>>>(Cc, w_f, b_f, F1, 256,
                                                   16384);
  conv1x1_tile<<<dim3(16, 8, 4), blk, 0, stream>>>(Cc, w_g, b_g, F2, 256,
                                                   16384);
  conv1x1_tile<<<dim3(16, 64, 4), blk, 0, stream>>>(Cc, w_h, b_h, E, 256,
                                                    16384);
  win_attn_kernel<<<dim3(32, 32, 4), blk, 0, stream>>>(F1, F2, E, out_attn);
  // ---- d1: convT 256->128, AdaLIN, relu (bf16 out) ----
  convt3x3_tile<float, bf16><<<dim3(64, 32, 4), blk, 0, stream>>>(
      Cc, w_d1, b_d1, Bb2, 256, 128, 128);
  reduce_nc_kernel<bf16><<<512, blk, 0, stream>>>(Bb2, stats, 65536);
  adalin_coef_kernel<<<2, 256, 0, stream>>>(stats, rho4, gam4, bet4, 4, 128,
                                            1.f / 65536.f);
  scale_shift_kernel<bf16><<<131072, blk, 0, stream>>>(Bb2, stats, 65536,
                                                       (size_t)33554432, 1);
  // ---- d2: convT 128->64, AdaLIN, relu (bf16) ----
  convt3x3_tile<bf16, bf16><<<dim3(256, 16, 4), blk, 0, stream>>>(
      Bb2, w_d2, b_d2, A2, 128, 256, 256);
  reduce_nc_kernel<bf16><<<256, blk, 0, stream>>>(A2, stats, 262144);
  adalin_coef_kernel<<<1, 256, 0, stream>>>(stats, rho5, gam5, bet5, 4, 64,
                                            1.f / 262144.f);
  scale_shift_kernel<bf16><<<262144, blk, 0, stream>>>(A2, stats, 262144,
                                                       (size_t)67108864, 1);
  // ---- head: 7x7 conv + tanh -> fp32 img (overwrites stats scratch) ----
  conv7_tile<2, 3, bf16><<<dim3(256, 1, 4), blk, 0, stream>>>(
      A2, w_d3, b_d3, stats, out_img, 64, 512, 512, 0);
}

// Round 4
// 11664.783 us; speedup vs baseline: 2.2512x; 1.0742x over previous
//
#include <hip/hip_runtime.h>
#include <hip/hip_bf16.h>
#include <hip/hip_fp16.h>

#define EPSN 1e-5f

typedef __hip_bfloat16 bf16;
typedef __half f16;
typedef __attribute__((ext_vector_type(8))) short bf16x8;
typedef __attribute__((ext_vector_type(4))) float f32x4;

__device__ __forceinline__ float b2f(bf16 v) { return __bfloat162float(v); }
__device__ __forceinline__ bf16 f2b(float v) { return __float2bfloat16(v); }
__device__ __forceinline__ unsigned short f2bu(float v) {
  bf16 h = __float2bfloat16(v);
  return *reinterpret_cast<unsigned short*>(&h);
}
__device__ __forceinline__ float bu2f(unsigned short u) {
  unsigned int b = ((unsigned int)u) << 16;
  return __uint_as_float(b);
}
__device__ __forceinline__ unsigned short f2hu(float v) {
  f16 h = __float2half(v);
  return *reinterpret_cast<unsigned short*>(&h);
}
__device__ __forceinline__ float hu2f(unsigned short u) {
  f16 h = *reinterpret_cast<f16*>(&u);
  return __half2float(h);
}
__device__ __forceinline__ void stv(bf16* p, size_t i, float v) { p[i] = f2b(v); }
__device__ __forceinline__ void stv(float* p, size_t i, float v) { p[i] = v; }
__device__ __forceinline__ void stv(f16* p, size_t i, float v) {
  p[i] = __float2half(v);
}

// vec4 load/store helpers (fp32/bf16/fp16 storage, fp32 compute)
__device__ __forceinline__ float4 ld4(const float* p) { return *(const float4*)p; }
__device__ __forceinline__ float4 ld4(const bf16* p) {
  ushort4 u = *(const ushort4*)p;
  float4 r;
  r.x = bu2f(u.x);
  r.y = bu2f(u.y);
  r.z = bu2f(u.z);
  r.w = bu2f(u.w);
  return r;
}
__device__ __forceinline__ float4 ld4(const f16* p) {
  ushort4 u = *(const ushort4*)p;
  float4 r;
  r.x = hu2f(u.x);
  r.y = hu2f(u.y);
  r.z = hu2f(u.z);
  r.w = hu2f(u.w);
  return r;
}
__device__ __forceinline__ void st4(float* p, float4 v) { *(float4*)p = v; }
__device__ __forceinline__ void st4(bf16* p, float4 v) {
  uint2 o;
  o.x = (unsigned)f2bu(v.x) | ((unsigned)f2bu(v.y) << 16);
  o.y = (unsigned)f2bu(v.z) | ((unsigned)f2bu(v.w) << 16);
  *(uint2*)p = o;
}
__device__ __forceinline__ void st4(f16* p, float4 v) {
  ushort4 o = {f2hu(v.x), f2hu(v.y), f2hu(v.z), f2hu(v.w)};
  *(ushort4*)p = o;
}

// ---------------- zero the stats scratch (atomicAdd target) -----------------
__global__ void zero_stats_kernel(float* __restrict__ stats) {
  for (int k = threadIdx.x; k < 2048; k += 256) stats[k] = 0.f;
}

// ------- weight convert: [Co][Ci][3][3] fp32 -> [tap][co][ci] bf16 hi+lo ----
__global__ __launch_bounds__(256) void convert_w_kernel(
    const float* __restrict__ rw1, const float* __restrict__ rw2,
    unsigned short* __restrict__ wb) {
  int i = blockIdx.x * 256 + threadIdx.x;  // < 8*9*65536 = 4718592
  if (i >= 4718592) return;
  int conv = i / 589824;
  int rem = i % 589824;
  int tap = rem / 65536;
  int cc = rem % 65536;  // co*256+ci
  const float* src = ((conv & 1) ? rw2 : rw1) + (size_t)(conv >> 1) * 589824;
  float v = src[(size_t)cc * 9 + tap];
  bf16 h = __float2bfloat16(v);
  float fh = __bfloat162float(h);
  wb[i] = *reinterpret_cast<unsigned short*>(&h);
  bf16 l = __float2bfloat16(v - fh);
  wb[4718592 + i] = *reinterpret_cast<unsigned short*>(&l);
}

// ---------------- 3x3 s1 p1 conv via MFMA (bf16x3), Ci=Co=256, H=W=128 ------
__device__ __forceinline__ int swz3(int idx) {
  return (idx & 3) ^ ((idx >> 2) & 1);
}

__global__ __launch_bounds__(256) void conv3x3s1_mfma(
    const float* __restrict__ x, const unsigned short* __restrict__ wh,
    const unsigned short* __restrict__ wl, const float* __restrict__ bias,
    float* __restrict__ y) {
  const int H = 128, W = 128;
  int r = blockIdx.x;    // output row
  int cog = blockIdx.y;  // 0..1 (128 co each)
  int n = blockIdx.z;
  int tid = threadIdx.x;
  int wv = tid >> 6, lane = tid & 63;
  int wco = (wv >> 1) * 64, wpx = (wv & 1) * 64;
  int l15 = lane & 15, l4 = lane >> 4;

  __shared__ __align__(16) unsigned short Xh[3 * 130 * 32];
  __shared__ __align__(16) unsigned short Xl[3 * 130 * 32];
  __shared__ __align__(16) unsigned short Ah[128 * 32];
  __shared__ __align__(16) unsigned short Al[128 * 32];

  f32x4 acc[4][4];
#pragma unroll
  for (int m = 0; m < 4; ++m)
#pragma unroll
    for (int nf = 0; nf < 4; ++nf) acc[m][nf] = (f32x4){0.f, 0.f, 0.f, 0.f};

  const float* xn0 = x + (size_t)n * 256 * H * W;

  for (int cb = 0; cb < 8; ++cb) {
    int ci0 = cb * 32;
    {
      const float* xn = xn0 + (size_t)ci0 * H * W;
      for (int t = tid; t < 1560; t += 256) {
        int q = t & 3;
        int cr = t >> 2;     // 0..389
        int col = cr % 130;  // 0..129
        int row = cr / 130;  // 0..2
        int gr = r + row - 1;
        int gc = col - 1;
        bool ok = (gr >= 0) && (gr < H) && (gc >= 0) && (gc < W);
        uint4 ph = {0, 0, 0, 0};
        uint4 pl = {0, 0, 0, 0};
        if (ok) {
          const float* xp =
              xn + (size_t)(q * 8) * (H * W) + (size_t)gr * W + gc;
          unsigned short vh[8], vl[8];
#pragma unroll
          for (int e = 0; e < 8; ++e) {
            float v = xp[(size_t)e * H * W];
            bf16 hb = __float2bfloat16(v);
            float fh = __bfloat162float(hb);
            bf16 lb = __float2bfloat16(v - fh);
            vh[e] = *reinterpret_cast<unsigned short*>(&hb);
            vl[e] = *reinterpret_cast<unsigned short*>(&lb);
          }
          ph.x = (unsigned)vh[0] | ((unsigned)vh[1] << 16);
          ph.y = (unsigned)vh[2] | ((unsigned)vh[3] << 16);
          ph.z = (unsigned)vh[4] | ((unsigned)vh[5] << 16);
          ph.w = (unsigned)vh[6] | ((unsigned)vh[7] << 16);
          pl.x = (unsigned)vl[0] | ((unsigned)vl[1] << 16);
          pl.y = (unsigned)vl[2] | ((unsigned)vl[3] << 16);
          pl.z = (unsigned)vl[4] | ((unsigned)vl[5] << 16);
          pl.w = (unsigned)vl[6] | ((unsigned)vl[7] << 16);
        }
        int slot = (cr * 4 + (q ^ swz3(col))) * 8;
        *(uint4*)(&Xh[slot]) = ph;
        *(uint4*)(&Xl[slot]) = pl;
      }
    }
    for (int tap = 0; tap < 9; ++tap) {
      for (int t = tid; t < 1024; t += 256) {
        int half = t >> 9;
        int rem = t & 511;
        int q = rem & 3;
        int co = rem >> 2;
        const unsigned short* wsrc =
            (half ? wl : wh) +
            ((size_t)tap * 256 + cog * 128 + co) * 256 + ci0 + q * 8;
        uint4 pk = *(const uint4*)wsrc;
        int slot = (co * 4 + (q ^ swz3(co))) * 8;
        *(uint4*)((half ? Al : Ah) + slot) = pk;
      }
      __syncthreads();
      int ky = tap / 3;
      int kx = tap - ky * 3;
      bf16x8 ahf[4], alf[4], bhf[4], blf[4];
#pragma unroll
      for (int m = 0; m < 4; ++m) {
        int co = wco + m * 16 + l15;
        int slot = (co * 4 + (l4 ^ swz3(co))) * 8;
        ahf[m] = *(const bf16x8*)(&Ah[slot]);
        alf[m] = *(const bf16x8*)(&Al[slot]);
      }
#pragma unroll
      for (int nf = 0; nf < 4; ++nf) {
        int col = wpx + nf * 16 + l15 + kx;  // lds col = px + kx
        int slot = ((ky * 130 + col) * 4 + (l4 ^ swz3(col))) * 8;
        bhf[nf] = *(const bf16x8*)(&Xh[slot]);
        blf[nf] = *(const bf16x8*)(&Xl[slot]);
      }
#pragma unroll
      for (int m = 0; m < 4; ++m)
#pragma unroll
        for (int nf = 0; nf < 4; ++nf) {
          acc[m][nf] = __builtin_amdgcn_mfma_f32_16x16x32_bf16(
              ahf[m], bhf[nf], acc[m][nf], 0, 0, 0);
          acc[m][nf] = __builtin_amdgcn_mfma_f32_16x16x32_bf16(
              ahf[m], blf[nf], acc[m][nf], 0, 0, 0);
          acc[m][nf] = __builtin_amdgcn_mfma_f32_16x16x32_bf16(
              alf[m], bhf[nf], acc[m][nf], 0, 0, 0);
        }
      __syncthreads();
    }
  }
#pragma unroll
  for (int m = 0; m < 4; ++m) {
    int cob = cog * 128 + wco + m * 16 + l4 * 4;
#pragma unroll
    for (int reg = 0; reg < 4; ++reg) {
      float bv = bias[cob + reg];
      float* yr =
          y + (((size_t)(n * 256 + cob + reg) * H) + r) * W + wpx + l15;
#pragma unroll
      for (int nf = 0; nf < 4; ++nf) yr[nf * 16] = acc[m][nf][reg] + bv;
    }
  }
}

// ---------------- 7x7 conv p3, 8 px x CO_T co, weights staged in LDS --------
// MODE 0: conv -> store RAW Tout + per-(n,co) sum/sumsq atomicAdd
// MODE 2: conv -> tanh -> fp32
template <int MODE, int CO_T, int CI, typename Tin, typename Tout>
__global__ __launch_bounds__(256) void conv7_tile(
    const Tin* __restrict__ x, const float* __restrict__ w,
    const float* __restrict__ bias, float* __restrict__ stats,
    Tout* __restrict__ y, int H, int W) {
  const int P = 8;
  __shared__ float wsh[CO_T * CI * 49];
  __shared__ float ss[256], qq[256];
  int cog = blockIdx.y;
  int Co = gridDim.y * CO_T;
  int n = blockIdx.z;
  int tid = threadIdx.x;
  for (int t = tid; t < CO_T * CI * 49; t += 256)
    wsh[t] = w[(size_t)cog * CO_T * CI * 49 + t];
  __syncthreads();
  int CG = W / P;      // 64
  int rpb = 256 / CG;  // 4
  int r = blockIdx.x * rpb + tid / CG;
  int c0 = (tid % CG) * P;
  const Tin* xb = x + (size_t)n * CI * H * W;
  int cr[7];
  float mr[7];
#pragma unroll
  for (int i = 0; i < 7; ++i) {
    int rr = r - 3 + i;
    mr[i] = (rr >= 0 && rr < H) ? 1.f : 0.f;
    cr[i] = min(max(rr, 0), H - 1);
  }
  int cc[14];
  float mc[14];
#pragma unroll
  for (int k = 0; k < 14; ++k) {
    int c = c0 - 3 + k;
    mc[k] = (c >= 0 && c < W) ? 1.f : 0.f;
    cc[k] = min(max(c, 0), W - 1);
  }
  float acc[CO_T][P];
#pragma unroll
  for (int j = 0; j < CO_T; ++j) {
    float b = bias[cog * CO_T + j];
#pragma unroll
    for (int p = 0; p < P; ++p) acc[j][p] = b;
  }
  for (int ci = 0; ci < CI; ++ci) {
    const Tin* xc = xb + (size_t)ci * H * W;
#pragma unroll
    for (int i = 0; i < 7; ++i) {
      const Tin* xr = xc + (size_t)cr[i] * W;
      float v[14];
#pragma unroll
      for (int k = 0; k < 14; ++k) v[k] = (float)xr[cc[k]] * (mr[i] * mc[k]);
#pragma unroll
      for (int j = 0; j < CO_T; ++j) {
        const float* wr = &wsh[(j * CI + ci) * 49 + i * 7];
#pragma unroll
        for (int p = 0; p < P; ++p) {
          acc[j][p] += v[p] * wr[0] + v[p + 1] * wr[1] + v[p + 2] * wr[2] +
                       v[p + 3] * wr[3] + v[p + 4] * wr[4] + v[p + 5] * wr[5] +
                       v[p + 6] * wr[6];
        }
      }
    }
  }
  if (MODE == 0) {
#pragma unroll
    for (int j = 0; j < CO_T; ++j) {
      int co = cog * CO_T + j;
      Tout* yr = y + ((size_t)(n * Co + co) * H + r) * W + c0;
      float4 o1 = {acc[j][0], acc[j][1], acc[j][2], acc[j][3]};
      float4 o2 = {acc[j][4], acc[j][5], acc[j][6], acc[j][7]};
      st4(yr, o1);
      st4(yr + 4, o2);
      float s = 0.f, q = 0.f;
#pragma unroll
      for (int p = 0; p < P; ++p) {
        s += acc[j][p];
        q += acc[j][p] * acc[j][p];
      }
      ss[tid] = s;
      qq[tid] = q;
      __syncthreads();
      for (int off = 128; off > 0; off >>= 1) {
        if (tid < off) {
          ss[tid] += ss[tid + off];
          qq[tid] += qq[tid + off];
        }
        __syncthreads();
      }
      if (tid == 0) {
        atomicAdd(&stats[n * Co + co], ss[0]);
        atomicAdd(&stats[1024 + n * Co + co], qq[0]);
      }
      __syncthreads();
    }
  } else {
#pragma unroll
    for (int j = 0; j < CO_T; ++j) {
      int co = cog * CO_T + j;
      Tout* yr = y + ((size_t)(n * Co + co) * H + r) * W + c0;
      float4 o1, o2;
      o1.x = tanhf(acc[j][0]);
      o1.y = tanhf(acc[j][1]);
      o1.z = tanhf(acc[j][2]);
      o1.w = tanhf(acc[j][3]);
      o2.x = tanhf(acc[j][4]);
      o2.y = tanhf(acc[j][5]);
      o2.z = tanhf(acc[j][6]);
      o2.w = tanhf(acc[j][7]);
      st4(yr, o1);
      st4(yr + 4, o2);
    }
  }
}

// ---------------- 3x3 s2 p1 conv, tiled 4 px x 4 co ------------------------
// NORM: input v = relu(x*sc[n,ci] + sh[n,ci]) fused from stats (AdaLIN coefs)
template <typename Tin, typename Tout, bool NORM>
__global__ __launch_bounds__(256) void conv3x3s2_tile(
    const Tin* __restrict__ x, const float* __restrict__ w,
    const float* __restrict__ bias, const float* __restrict__ stats,
    Tout* __restrict__ y, int Ci, int Hi, int Wi) {
  int Ho = Hi >> 1, Wo = Wi >> 1;
  int cog = blockIdx.y;
  int Co = gridDim.y * 4;
  int n = blockIdx.z;
  int CG = Wo >> 2;
  int rpb = 256 / CG;
  int tid = threadIdx.x;
  int r = blockIdx.x * rpb + tid / CG;
  int c0 = (tid % CG) * 4;
  const Tin* xb = x + (size_t)n * Ci * Hi * Wi;
  int ir0 = 2 * r - 1;
  float mr0 = (ir0 >= 0) ? 1.f : 0.f;
  int cr0 = max(ir0, 0);
  int icl = 2 * c0 - 1;
  float mcl = (icl >= 0) ? 1.f : 0.f;
  int ccl = max(icl, 0);
  float acc[4][4];
#pragma unroll
  for (int j = 0; j < 4; ++j) {
    float b = bias[cog * 4 + j];
#pragma unroll
    for (int p = 0; p < 4; ++p) acc[j][p] = b;
  }
  for (int ci = 0; ci < Ci; ++ci) {
    const Tin* xc = xb + (size_t)ci * Hi * Wi;
    float sc = 1.f, sh = 0.f;
    if (NORM) {
      sc = stats[2048 + n * Ci + ci];
      sh = stats[3072 + n * Ci + ci];
    }
    float v[3][9];
#pragma unroll
    for (int i = 0; i < 3; ++i) {
      int rr = (i == 0) ? cr0 : (2 * r - 1 + i);
      float mi = (i == 0) ? mr0 : 1.f;
      const Tin* xr = xc + (size_t)rr * Wi;
      float t[9];
      t[0] = (float)xr[ccl];
      float4 a = ld4(xr + 2 * c0);
      float4 b4 = ld4(xr + 2 * c0 + 4);
      t[1] = a.x;
      t[2] = a.y;
      t[3] = a.z;
      t[4] = a.w;
      t[5] = b4.x;
      t[6] = b4.y;
      t[7] = b4.z;
      t[8] = b4.w;
      if (NORM) {
#pragma unroll
        for (int k = 0; k < 9; ++k) t[k] = fmaxf(fmaf(t[k], sc, sh), 0.f);
      }
      v[i][0] = t[0] * (mcl * mi);
#pragma unroll
      for (int k = 1; k < 9; ++k) v[i][k] = t[k] * mi;
    }
#pragma unroll
    for (int j = 0; j < 4; ++j) {
      const float* wc = w + ((size_t)(cog * 4 + j) * Ci + ci) * 9;
#pragma unroll
      for (int p = 0; p < 4; ++p) {
        acc[j][p] += v[0][2 * p] * wc[0] + v[0][2 * p + 1] * wc[1] +
                     v[0][2 * p + 2] * wc[2] + v[1][2 * p] * wc[3] +
                     v[1][2 * p + 1] * wc[4] + v[1][2 * p + 2] * wc[5] +
                     v[2][2 * p] * wc[6] + v[2][2 * p + 1] * wc[7] +
                     v[2][2 * p + 2] * wc[8];
      }
    }
  }
#pragma unroll
  for (int j = 0; j < 4; ++j) {
    float4 o = {acc[j][0], acc[j][1], acc[j][2], acc[j][3]};
    st4(y + ((size_t)(n * Co + cog * 4 + j) * Ho + r) * Wo + c0, o);
  }
}

// ---------------- 1x1 conv, tiled 4 px x 4 co, fp32 -------------------------
__global__ __launch_bounds__(256) void conv1x1_tile(
    const float* __restrict__ x, const float* __restrict__ w,
    const float* __restrict__ bias, float* __restrict__ y, int Ci, int HW) {
  int cog = blockIdx.y;
  int Co = gridDim.y * 4;
  int n = blockIdx.z;
  int p0 = (blockIdx.x * 256 + threadIdx.x) * 4;
  const float* xb = x + (size_t)n * Ci * HW + p0;
  float acc[4][4];
#pragma unroll
  for (int j = 0; j < 4; ++j) {
    float b = bias[cog * 4 + j];
#pragma unroll
    for (int p = 0; p < 4; ++p) acc[j][p] = b;
  }
  for (int ci = 0; ci < Ci; ++ci) {
    float4 xv = *(const float4*)(xb + (size_t)ci * HW);
#pragma unroll
    for (int j = 0; j < 4; ++j) {
      float wv = w[(size_t)(cog * 4 + j) * Ci + ci];
      acc[j][0] += xv.x * wv;
      acc[j][1] += xv.y * wv;
      acc[j][2] += xv.z * wv;
      acc[j][3] += xv.w * wv;
    }
  }
#pragma unroll
  for (int j = 0; j < 4; ++j) {
    float4 o = {acc[j][0], acc[j][1], acc[j][2], acc[j][3]};
    *(float4*)(y + (size_t)(n * Co + cog * 4 + j) * HW + p0) = o;
  }
}

// ---------------- ConvTranspose2d k3 s2 p1 op1, tiled 2x2 quad x 4 co -------
template <typename Tin, typename Tout>
__global__ __launch_bounds__(256) void convt3x3_tile(
    const Tin* __restrict__ x, const float* __restrict__ w,
    const float* __restrict__ bias, Tout* __restrict__ y, int Ci, int Hi,
    int Wi) {
  int Ho = Hi * 2, Wo = Wi * 2;
  int cog = blockIdx.y;
  int Co = gridDim.y * 4;
  int n = blockIdx.z;
  int q = blockIdx.x * 256 + threadIdx.x;
  int yq = q / Wi, xq = q % Wi;
  const Tin* xb = x + (size_t)n * Ci * Hi * Wi;
  float mx = (xq + 1 < Wi) ? 1.f : 0.f;
  int x1 = min(xq + 1, Wi - 1);
  float my = (yq + 1 < Hi) ? 1.f : 0.f;
  int y1 = min(yq + 1, Hi - 1);
  float mxy = mx * my;
  float acc[4][4];
#pragma unroll
  for (int j = 0; j < 4; ++j) {
    float b = bias[cog * 4 + j];
#pragma unroll
    for (int p = 0; p < 4; ++p) acc[j][p] = b;
  }
  for (int ci = 0; ci < Ci; ++ci) {
    const Tin* xc = xb + (size_t)ci * Hi * Wi;
    float a = (float)xc[(size_t)yq * Wi + xq];
    float bv = (float)xc[(size_t)yq * Wi + x1] * mx;
    float c = (float)xc[(size_t)y1 * Wi + xq] * my;
    float d = (float)xc[(size_t)y1 * Wi + x1] * mxy;
#pragma unroll
    for (int j = 0; j < 4; ++j) {
      const float* wc = w + ((size_t)ci * Co + cog * 4 + j) * 9;
      acc[j][0] += a * wc[4];
      acc[j][1] += bv * wc[3] + a * wc[5];
      acc[j][2] += c * wc[1] + a * wc[7];
      acc[j][3] += d * wc[0] + c * wc[2] + bv * wc[6] + a * wc[8];
    }
  }
#pragma unroll
  for (int j = 0; j < 4; ++j) {
    size_t base = ((size_t)(n * Co + cog * 4 + j) * Ho + 2 * yq) * Wo + 2 * xq;
    stv(y, base, acc[j][0]);
    stv(y, base + 1, acc[j][1]);
    stv(y, base + Wo, acc[j][2]);
    stv(y, base + Wo + 1, acc[j][3]);
  }
}

// ---------------- per-(n,c) sum / sumsq reduction ---------------------------
template <typename Tin>
__global__ __launch_bounds__(256) void reduce_nc_kernel(
    const Tin* __restrict__ x, float* __restrict__ stats, int HW) {
  int b = blockIdx.x;
  const Tin* p = x + (size_t)b * HW;
  float s = 0.f, q = 0.f;
  for (int i = threadIdx.x; i < HW; i += 256) {
    float v = (float)p[i];
    s += v;
    q += v * v;
  }
  __shared__ float ss[256], qq[256];
  ss[threadIdx.x] = s;
  qq[threadIdx.x] = q;
  __syncthreads();
  for (int off = 128; off > 0; off >>= 1) {
    if (threadIdx.x < off) {
      ss[threadIdx.x] += ss[threadIdx.x + off];
      qq[threadIdx.x] += qq[threadIdx.x + off];
    }
    __syncthreads();
  }
  if (threadIdx.x == 0) {
    stats[b] = ss[0];
    stats[1024 + b] = qq[0];
  }
}

// ---------------- AdaLIN coefficients ---------------------------------------
__global__ void adalin_coef_kernel(float* __restrict__ stats,
                                   const float* __restrict__ rho,
                                   const float* __restrict__ gam,
                                   const float* __restrict__ bet, int N, int C,
                                   float invHW) {
  int i = blockIdx.x * blockDim.x + threadIdx.x;
  if (i >= N * C) return;
  int c = i % C;
  const float* sums = stats;
  const float* sqs = stats + 1024;
  float im = sums[i] * invHW;
  float iv = sqs[i] * invHW - im * im;
  float lsum = 0.f, lsq = 0.f;
  for (int n = 0; n < N; ++n) {
    lsum += sums[n * C + c];
    lsq += sqs[n * C + c];
  }
  float lm = lsum * invHW / N;
  float lv = lsq * invHW / N - lm * lm;
  float r = rho[c];
  float mean = r * im + (1.f - r) * lm;
  float var = fmaxf(r * iv + (1.f - r) * lv, 0.f);
  float sc = gam[c] / sqrtf(var + EPSN);
  stats[2048 + i] = sc;
  stats[3072 + i] = bet[c] - mean * sc;
}

// ---------------- InstanceNorm coefficients ---------------------------------
__global__ void inorm_coef_kernel(float* __restrict__ stats, int NC,
                                  float invHW) {
  int i = blockIdx.x * blockDim.x + threadIdx.x;
  if (i >= NC) return;
  float im = stats[i] * invHW;
  float iv = fmaxf(stats[1024 + i] * invHW - im * im, 0.f);
  float sc = 1.f / sqrtf(iv + EPSN);
  stats[2048 + i] = sc;
  stats[3072 + i] = -im * sc;
}

// ---------------- x = (relu?)(x*scale[nc] + shift[nc])  (in-place) ----------
template <typename T>
__global__ __launch_bounds__(256) void scale_shift_kernel(
    T* __restrict__ x, const float* __restrict__ stats, int HW, size_t total,
    int relu) {
  size_t i = (size_t)blockIdx.x * 256 + threadIdx.x;
  if (i >= total) return;
  int nc = (int)(i / (size_t)HW);
  float v = (float)x[i] * stats[2048 + nc] + stats[3072 + nc];
  if (relu) v = fmaxf(v, 0.f);
  stv(x, i, v);
}

// ---------------- dst = relu(dst + a)  (fp32) -------------------------------
__global__ __launch_bounds__(256) void add_relu_kernel(
    float* __restrict__ dst, const float* __restrict__ a, size_t total) {
  size_t i = (size_t)blockIdx.x * 256 + threadIdx.x;
  if (i >= total) return;
  dst[i] = fmaxf(dst[i] + a[i], 0.f);
}

// ---------------- windowed attention (all fp32) -----------------------------
__global__ __launch_bounds__(256) void win_attn_kernel(
    const float* __restrict__ f, const float* __restrict__ g,
    const float* __restrict__ h, float* __restrict__ out) {
  const int H = 128;
  int j = blockIdx.x;
  int i = blockIdx.y;
  int b = blockIdx.z;
  __shared__ float fs[32 * 64];
  __shared__ float gs[32 * 64];
  __shared__ float att[16 * 64];
  int t = threadIdx.x;
  for (int idx = t; idx < 32 * 64; idx += 256) {
    int c = idx >> 6, k = idx & 63;
    int hr = i * 4 + (k >> 3), wc = j * 4 + (k & 7);
    float fv = 0.f, gv = 0.f;
    if (hr < H && wc < H) {
      size_t o = ((size_t)(b * 32 + c) * H + hr) * H + wc;
      fv = f[o];
      gv = g[o];
    }
    fs[idx] = fv;
    gs[idx] = gv;
  }
  __syncthreads();
  for (int idx = t; idx < 1024; idx += 256) {
    int q = idx >> 6, k = idx & 63;
    int qi = (q >> 2) * 8 + (q & 3);
    int hr = i * 4 + (k >> 3), wc = j * 4 + (k & 7);
    float s;
    if (hr < H && wc < H) {
      s = 0.f;
      for (int c = 0; c < 32; ++c) s += fs[c * 64 + qi] * gs[c * 64 + k];
    } else {
      s = -1e30f;
    }
    att[idx] = s;
  }
  __syncthreads();
  if (t < 16) {
    float m = -1e30f;
    for (int k = 0; k < 64; ++k) m = fmaxf(m, att[t * 64 + k]);
    float d = 0.f;
    for (int k = 0; k < 64; ++k) {
      float e = expf(att[t * 64 + k] - m);
      att[t * 64 + k] = e;
      d += e;
    }
    float inv = 1.f / d;
    for (int k = 0; k < 64; ++k) att[t * 64 + k] *= inv;
  }
  __syncthreads();
  int c = t;
  float accs[16];
  for (int q = 0; q < 16; ++q) accs[q] = 0.f;
  const float* hb = h + (size_t)(b * 256 + c) * H * H;
  for (int k = 0; k < 64; ++k) {
    int hr = i * 4 + (k >> 3), wc = j * 4 + (k & 7);
    if (hr >= H || wc >= H) continue;
    float hv = hb[hr * H + wc];
    for (int q = 0; q < 16; ++q) accs[q] += hv * att[q * 64 + k];
  }
  for (int q = 0; q < 16; ++q) {
    int oh = i * 4 + (q >> 2), ow = j * 4 + (q & 3);
    out[((size_t)(b * 256 + c) * H + oh) * H + ow] = accs[q];
  }
}

// ============================================================================
extern "C" void kernel_launch(void* const* d_in, const int* in_sizes, int n_in,
                              void* d_out, int out_size, void* d_ws,
                              size_t ws_size, hipStream_t stream) {
  const float* x = (const float*)d_in[0];
  const float* w_e1 = (const float*)d_in[1];
  const float* b_e1 = (const float*)d_in[2];
  const float* rho1 = (const float*)d_in[3];
  const float* gam1 = (const float*)d_in[4];
  const float* bet1 = (const float*)d_in[5];
  const float* w_e2 = (const float*)d_in[6];
  const float* b_e2 = (const float*)d_in[7];
  const float* rho2 = (const float*)d_in[8];
  const float* gam2 = (const float*)d_in[9];
  const float* bet2 = (const float*)d_in[10];
  const float* w_e3 = (const float*)d_in[11];
  const float* b_e3 = (const float*)d_in[12];
  const float* rho3 = (const float*)d_in[13];
  const float* gam3 = (const float*)d_in[14];
  const float* bet3 = (const float*)d_in[15];
  const float* rw1 = (const float*)d_in[16];
  const float* rb1 = (const float*)d_in[17];
  const float* rw2 = (const float*)d_in[18];
  const float* rb2 = (const float*)d_in[19];
  const float* w_f = (const float*)d_in[20];
  const float* b_f = (const float*)d_in[21];
  const float* w_g = (const float*)d_in[22];
  const float* b_g = (const float*)d_in[23];
  const float* w_h = (const float*)d_in[24];
  const float* b_h = (const float*)d_in[25];
  const float* w_d1 = (const float*)d_in[26];
  const float* b_d1 = (const float*)d_in[27];
  const float* rho4 = (const float*)d_in[28];
  const float* gam4 = (const float*)d_in[29];
  const float* bet4 = (const float*)d_in[30];
  const float* w_d2 = (const float*)d_in[31];
  const float* b_d2 = (const float*)d_in[32];
  const float* rho5 = (const float*)d_in[33];
  const float* gam5 = (const float*)d_in[34];
  const float* bet5 = (const float*)d_in[35];
  const float* w_d3 = (const float*)d_in[36];
  const float* b_d3 = (const float*)d_in[37];

  // ws layout (192 MiB):
  // E1H f16 raw e1 [0,128MiB) (dead after e2)
  // B2H f16 raw e2 [128,192) (dead after e3; later Bb2 bf16 d1 out)
  // Cc fp32 [0,64), D fp32 [64,128), E fp32 [128,192) (residual stage)
  // F1/F2 fp32 [64,80) (attention f/g); A2 bf16 [0,128) (d2 out)
  char* wsb = (char*)d_ws;
  f16* E1H = (f16*)wsb;
  float* Cc = (float*)wsb;
  float* D = (float*)(wsb + 67108864);
  float* E = (float*)(wsb + 134217728);
  float* F1 = (float*)(wsb + 67108864);
  float* F2 = (float*)(wsb + 75497472);
  f16* B2H = (f16*)(wsb + 134217728);
  bf16* Bb2 = (bf16*)(wsb + 134217728);
  bf16* A2 = (bf16*)wsb;

  float* out_img = (float*)d_out;
  float* out_attn = out_img + 3145728;
  // 16 KiB stats scratch at head of img region; fully overwritten by head conv
  float* stats = (float*)d_out;
  // bf16 hi+lo residual weights scratch in the (not yet written) out_attn
  // region; fully consumed before win_attn_kernel writes out_attn.
  unsigned short* wbres = (unsigned short*)((char*)d_out + 12582912);

  dim3 blk(256);

  // ---- convert residual weights to bf16 hi+lo [tap][co][ci] (once) ----
  convert_w_kernel<<<18432, blk, 0, stream>>>(rw1, rw2, wbres);

  // ---- e1: 7x7 conv -> raw f16 + stats (single pass, all batches) ----
  zero_stats_kernel<<<1, 256, 0, stream>>>(stats);
  conv7_tile<0, 4, 3, float, f16><<<dim3(128, 16, 4), blk, 0, stream>>>(
      x, w_e1, b_e1, stats, E1H, 512, 512);
  adalin_coef_kernel<<<1, 256, 0, stream>>>(stats, rho1, gam1, bet1, 4, 64,
                                            1.f / 262144.f);
  // ---- e2: 3x3 s2 conv with fused e1-norm+relu -> raw f16 ----
  conv3x3s2_tile<f16, f16, true><<<dim3(64, 32, 4), blk, 0, stream>>>(
      E1H, w_e2, b_e2, stats, B2H, 64, 512, 512);
  reduce_nc_kernel<f16><<<512, blk, 0, stream>>>(B2H, stats, 65536);
  adalin_coef_kernel<<<2, 256, 0, stream>>>(stats, rho2, gam2, bet2, 4, 128,
                                            1.f / 65536.f);
  // ---- e3: 3x3 s2 conv with fused e2-norm+relu -> fp32, then AdaLIN ----
  conv3x3s2_tile<f16, float, true><<<dim3(16, 64, 4), blk, 0, stream>>>(
      B2H, w_e3, b_e3, stats, Cc, 128, 256, 256);
  reduce_nc_kernel<float><<<1024, blk, 0, stream>>>(Cc, stats, 16384);
  adalin_coef_kernel<<<4, 256, 0, stream>>>(stats, rho3, gam3, bet3, 4, 256,
                                            1.f / 16384.f);
  scale_shift_kernel<float><<<65536, blk, 0, stream>>>(Cc, stats, 16384,
                                                       (size_t)16777216, 1);
  // ---- 4 residual blocks (bf16x3 MFMA convs) ----
  for (int r = 0; r < 4; ++r) {
    const float* rb1p = rb1 + (size_t)r * 256;
    const float* rb2p = rb2 + (size_t)r * 256;
    const unsigned short* w1h = wbres + (size_t)(r * 2) * 589824;
    const unsigned short* w1l = w1h + 4718592;
    const unsigned short* w2h = wbres + (size_t)(r * 2 + 1) * 589824;
    const unsigned short* w2l = w2h + 4718592;
    conv3x3s1_mfma<<<dim3(128, 2, 4), blk, 0, stream>>>(Cc, w1h, w1l, rb1p, D);
    reduce_nc_kernel<float><<<1024, blk, 0, stream>>>(D, stats, 16384);
    inorm_coef_kernel<<<4, 256, 0, stream>>>(stats, 1024, 1.f / 16384.f);
    scale_shift_kernel<float><<<65536, blk, 0, stream>>>(D, stats, 16384,
                                                         (size_t)16777216, 1);
    conv3x3s1_mfma<<<dim3(128, 2, 4), blk, 0, stream>>>(D, w2h, w2l, rb2p, E);
    reduce_nc_kernel<float><<<1024, blk, 0, stream>>>(E, stats, 16384);
    inorm_coef_kernel<<<4, 256, 0, stream>>>(stats, 1024, 1.f / 16384.f);
    scale_shift_kernel<float><<<65536, blk, 0, stream>>>(E, stats, 16384,
                                                         (size_t)16777216, 0);
    add_relu_kernel<<<65536, blk, 0, stream>>>(Cc, E, (size_t)16777216);
  }
  // ---- attention: 1x1 convs f/g/h + windowed attention ----
  conv1x1_tile<<<dim3(16, 8, 4), blk, 0, stream>>>(Cc, w_f, b_f, F1, 256,
                                                   16384);
  conv1x1_tile<<<dim3(16, 8, 4), blk, 0, stream>>>(Cc, w_g, b_g, F2, 256,
                                                   16384);
  conv1x1_tile<<<dim3(16, 64, 4), blk, 0, stream>>>(Cc, w_h, b_h, E, 256,
                                                    16384);
  win_attn_kernel<<<dim3(32, 32, 4), blk, 0, stream>>>(F1, F2, E, out_attn);
  // ---- d1: convT 256->128, AdaLIN, relu (bf16 out) ----
  convt3x3_tile<float, bf16><<<dim3(64, 32, 4), blk, 0, stream>>>(
      Cc, w_d1, b_d1, Bb2, 256, 128, 128);
  reduce_nc_kernel<bf16><<<512, blk, 0, stream>>>(Bb2, stats, 65536);
  adalin_coef_kernel<<<2, 256, 0, stream>>>(stats, rho4, gam4, bet4, 4, 128,
                                            1.f / 65536.f);
  scale_shift_kernel<bf16><<<131072, blk, 0, stream>>>(Bb2, stats, 65536,
                                                       (size_t)33554432, 1);
  // ---- d2: convT 128->64, AdaLIN, relu (bf16) ----
  convt3x3_tile<bf16, bf16><<<dim3(256, 16, 4), blk, 0, stream>>>(
      Bb2, w_d2, b_d2, A2, 128, 256, 256);
  reduce_nc_kernel<bf16><<<256, blk, 0, stream>>>(A2, stats, 262144);
  adalin_coef_kernel<<<1, 256, 0, stream>>>(stats, rho5, gam5, bet5, 4, 64,
                                            1.f / 262144.f);
  scale_shift_kernel<bf16><<<262144, blk, 0, stream>>>(A2, stats, 262144,
                                                       (size_t)67108864, 1);
  // ---- head: 7x7 conv + tanh -> fp32 img (overwrites stats scratch) ----
  conv7_tile<2, 3, 64, bf16, float><<<dim3(128, 1, 4), blk, 0, stream>>>(
      A2, w_d3, b_d3, stats, out_img, 512, 512);
}

// Round 7
// 9432.532 us; speedup vs baseline: 2.7840x; 1.2367x over previous
//
#include <hip/hip_runtime.h>
#include <hip/hip_bf16.h>
#include <hip/hip_fp16.h>

#define EPSN 1e-5f

typedef __hip_bfloat16 bf16;
typedef __half f16;
typedef __attribute__((ext_vector_type(8))) short bf16x8;
typedef __attribute__((ext_vector_type(4))) float f32x4;

__device__ __forceinline__ float b2f(bf16 v) { return __bfloat162float(v); }
__device__ __forceinline__ bf16 f2b(float v) { return __float2bfloat16(v); }
__device__ __forceinline__ unsigned short f2bu(float v) {
  bf16 h = __float2bfloat16(v);
  return *reinterpret_cast<unsigned short*>(&h);
}
__device__ __forceinline__ float bu2f(unsigned short u) {
  unsigned int b = ((unsigned int)u) << 16;
  return __uint_as_float(b);
}
__device__ __forceinline__ unsigned short f2hu(float v) {
  f16 h = __float2half(v);
  return *reinterpret_cast<unsigned short*>(&h);
}
__device__ __forceinline__ float hu2f(unsigned short u) {
  f16 h = *reinterpret_cast<f16*>(&u);
  return __half2float(h);
}
__device__ __forceinline__ void stv(bf16* p, size_t i, float v) { p[i] = f2b(v); }
__device__ __forceinline__ void stv(float* p, size_t i, float v) { p[i] = v; }
__device__ __forceinline__ void stv(f16* p, size_t i, float v) {
  p[i] = __float2half(v);
}

// vec4 load/store helpers (fp32/bf16/fp16 storage, fp32 compute)
__device__ __forceinline__ float4 ld4(const float* p) { return *(const float4*)p; }
__device__ __forceinline__ float4 ld4(const bf16* p) {
  ushort4 u = *(const ushort4*)p;
  float4 r;
  r.x = bu2f(u.x);
  r.y = bu2f(u.y);
  r.z = bu2f(u.z);
  r.w = bu2f(u.w);
  return r;
}
__device__ __forceinline__ float4 ld4(const f16* p) {
  ushort4 u = *(const ushort4*)p;
  float4 r;
  r.x = hu2f(u.x);
  r.y = hu2f(u.y);
  r.z = hu2f(u.z);
  r.w = hu2f(u.w);
  return r;
}
__device__ __forceinline__ void st4(float* p, float4 v) { *(float4*)p = v; }
__device__ __forceinline__ void st4(bf16* p, float4 v) {
  uint2 o;
  o.x = (unsigned)f2bu(v.x) | ((unsigned)f2bu(v.y) << 16);
  o.y = (unsigned)f2bu(v.z) | ((unsigned)f2bu(v.w) << 16);
  *(uint2*)p = o;
}
__device__ __forceinline__ void st4(f16* p, float4 v) {
  ushort4 o = {f2hu(v.x), f2hu(v.y), f2hu(v.z), f2hu(v.w)};
  *(ushort4*)p = o;
}

// ---------------- zero the stats scratch (atomicAdd target) -----------------
__global__ void zero_stats_kernel(float* __restrict__ stats) {
  for (int k = threadIdx.x; k < 2048; k += 256) stats[k] = 0.f;
}

// ------- weight convert: [Co][Ci][3][3] fp32 -> [tap][co][ci] bf16 hi+lo ----
__global__ __launch_bounds__(256) void convert_w_kernel(
    const float* __restrict__ rw1, const float* __restrict__ rw2,
    unsigned short* __restrict__ wb) {
  int i = blockIdx.x * 256 + threadIdx.x;  // < 8*9*65536 = 4718592
  if (i >= 4718592) return;
  int conv = i / 589824;
  int rem = i % 589824;
  int tap = rem / 65536;
  int cc = rem % 65536;  // co*256+ci
  const float* src = ((conv & 1) ? rw2 : rw1) + (size_t)(conv >> 1) * 589824;
  float v = src[(size_t)cc * 9 + tap];
  bf16 h = __float2bfloat16(v);
  float fh = __bfloat162float(h);
  wb[i] = *reinterpret_cast<unsigned short*>(&h);
  bf16 l = __float2bfloat16(v - fh);
  wb[4718592 + i] = *reinterpret_cast<unsigned short*>(&l);
}

// ---------------- 3x3 s1 p1 conv via MFMA (bf16x3), Ci=Co=256, H=W=128 ------
__device__ __forceinline__ int swz3(int idx) {
  return (idx & 3) ^ ((idx >> 2) & 1);
}

__global__ __launch_bounds__(256) void conv3x3s1_mfma(
    const float* __restrict__ x, const unsigned short* __restrict__ wh,
    const unsigned short* __restrict__ wl, const float* __restrict__ bias,
    float* __restrict__ y) {
  const int H = 128, W = 128;
  int r = blockIdx.x;    // output row
  int cog = blockIdx.y;  // 0..1 (128 co each)
  int n = blockIdx.z;
  int tid = threadIdx.x;
  int wv = tid >> 6, lane = tid & 63;
  int wco = (wv >> 1) * 64, wpx = (wv & 1) * 64;
  int l15 = lane & 15, l4 = lane >> 4;

  __shared__ __align__(16) unsigned short Xh[3 * 130 * 32];
  __shared__ __align__(16) unsigned short Xl[3 * 130 * 32];
  __shared__ __align__(16) unsigned short Ah[128 * 32];
  __shared__ __align__(16) unsigned short Al[128 * 32];

  f32x4 acc[4][4];
#pragma unroll
  for (int m = 0; m < 4; ++m)
#pragma unroll
    for (int nf = 0; nf < 4; ++nf) acc[m][nf] = (f32x4){0.f, 0.f, 0.f, 0.f};

  const float* xn0 = x + (size_t)n * 256 * H * W;

  for (int cb = 0; cb < 8; ++cb) {
    int ci0 = cb * 32;
    {
      const float* xn = xn0 + (size_t)ci0 * H * W;
      for (int t = tid; t < 1560; t += 256) {
        int q = t & 3;
        int cr = t >> 2;     // 0..389
        int col = cr % 130;  // 0..129
        int row = cr / 130;  // 0..2
        int gr = r + row - 1;
        int gc = col - 1;
        bool ok = (gr >= 0) && (gr < H) && (gc >= 0) && (gc < W);
        uint4 ph = {0, 0, 0, 0};
        uint4 pl = {0, 0, 0, 0};
        if (ok) {
          const float* xp =
              xn + (size_t)(q * 8) * (H * W) + (size_t)gr * W + gc;
          unsigned short vh[8], vl[8];
#pragma unroll
          for (int e = 0; e < 8; ++e) {
            float v = xp[(size_t)e * H * W];
            bf16 hb = __float2bfloat16(v);
            float fh = __bfloat162float(hb);
            bf16 lb = __float2bfloat16(v - fh);
            vh[e] = *reinterpret_cast<unsigned short*>(&hb);
            vl[e] = *reinterpret_cast<unsigned short*>(&lb);
          }
          ph.x = (unsigned)vh[0] | ((unsigned)vh[1] << 16);
          ph.y = (unsigned)vh[2] | ((unsigned)vh[3] << 16);
          ph.z = (unsigned)vh[4] | ((unsigned)vh[5] << 16);
          ph.w = (unsigned)vh[6] | ((unsigned)vh[7] << 16);
          pl.x = (unsigned)vl[0] | ((unsigned)vl[1] << 16);
          pl.y = (unsigned)vl[2] | ((unsigned)vl[3] << 16);
          pl.z = (unsigned)vl[4] | ((unsigned)vl[5] << 16);
          pl.w = (unsigned)vl[6] | ((unsigned)vl[7] << 16);
        }
        int slot = (cr * 4 + (q ^ swz3(col))) * 8;
        *(uint4*)(&Xh[slot]) = ph;
        *(uint4*)(&Xl[slot]) = pl;
      }
    }
    for (int tap = 0; tap < 9; ++tap) {
      for (int t = tid; t < 1024; t += 256) {
        int half = t >> 9;
        int rem = t & 511;
        int q = rem & 3;
        int co = rem >> 2;
        const unsigned short* wsrc =
            (half ? wl : wh) +
            ((size_t)tap * 256 + cog * 128 + co) * 256 + ci0 + q * 8;
        uint4 pk = *(const uint4*)wsrc;
        int slot = (co * 4 + (q ^ swz3(co))) * 8;
        *(uint4*)((half ? Al : Ah) + slot) = pk;
      }
      __syncthreads();
      int ky = tap / 3;
      int kx = tap - ky * 3;
      bf16x8 ahf[4], alf[4], bhf[4], blf[4];
#pragma unroll
      for (int m = 0; m < 4; ++m) {
        int co = wco + m * 16 + l15;
        int slot = (co * 4 + (l4 ^ swz3(co))) * 8;
        ahf[m] = *(const bf16x8*)(&Ah[slot]);
        alf[m] = *(const bf16x8*)(&Al[slot]);
      }
#pragma unroll
      for (int nf = 0; nf < 4; ++nf) {
        int col = wpx + nf * 16 + l15 + kx;  // lds col = px + kx
        int slot = ((ky * 130 + col) * 4 + (l4 ^ swz3(col))) * 8;
        bhf[nf] = *(const bf16x8*)(&Xh[slot]);
        blf[nf] = *(const bf16x8*)(&Xl[slot]);
      }
#pragma unroll
      for (int m = 0; m < 4; ++m)
#pragma unroll
        for (int nf = 0; nf < 4; ++nf) {
          acc[m][nf] = __builtin_amdgcn_mfma_f32_16x16x32_bf16(
              ahf[m], bhf[nf], acc[m][nf], 0, 0, 0);
          acc[m][nf] = __builtin_amdgcn_mfma_f32_16x16x32_bf16(
              ahf[m], blf[nf], acc[m][nf], 0, 0, 0);
          acc[m][nf] = __builtin_amdgcn_mfma_f32_16x16x32_bf16(
              alf[m], bhf[nf], acc[m][nf], 0, 0, 0);
        }
      __syncthreads();
    }
  }
#pragma unroll
  for (int m = 0; m < 4; ++m) {
    int cob = cog * 128 + wco + m * 16 + l4 * 4;
#pragma unroll
    for (int reg = 0; reg < 4; ++reg) {
      float bv = bias[cob + reg];
      float* yr =
          y + (((size_t)(n * 256 + cob + reg) * H) + r) * W + wpx + l15;
#pragma unroll
      for (int nf = 0; nf < 4; ++nf) yr[nf * 16] = acc[m][nf][reg] + bv;
    }
  }
}

// ---------------- e1: 7x7 conv p3, CI=3, LDS-tiled (1 ci slice at a time) ---
// 8co x 8px(interleaved), raw f16 out + stats. Block: 4 rows x 512 cols.
// grid (128, 8, 4). LDS: 20.8K (Xs) + 4.7K (wsh) + 0.25K = 25.8 KB.
__global__ __launch_bounds__(256) void conv7_e1(
    const float* __restrict__ x, const float* __restrict__ w,
    const float* __restrict__ bias, float* __restrict__ stats,
    f16* __restrict__ y) {
  const int H = 512, W = 512;
  __shared__ float Xs[5200];         // [10][520] one ci, zero-padded halo
  __shared__ float wsh[8 * 3 * 49];  // 8 co slab
  __shared__ float sred[4][8], qred[4][8];
  int cog = blockIdx.y;  // 8 groups x 8 co
  int n = blockIdx.z;
  int tid = threadIdx.x;
  int r0 = blockIdx.x * 4;
  int tr = tid >> 6;
  int lane = tid & 63;
  for (int t = tid; t < 1176; t += 256) wsh[t] = w[cog * 1176 + t];
  const float* xb = x + (size_t)n * 3 * H * W;
  float acc[8][8];
#pragma unroll
  for (int j = 0; j < 8; ++j) {
#pragma unroll
    for (int p = 0; p < 8; ++p) acc[j][p] = 0.f;
  }
  for (int ci = 0; ci < 3; ++ci) {
    __syncthreads();  // protect Xs from prev readers; orders wsh on 1st iter
    for (int t = tid; t < 5200; t += 256) {
      int row = t / 520;
      int col = t - row * 520;
      int gr = r0 - 3 + row;
      int gc = col - 3;
      float v = 0.f;
      if (gr >= 0 && gr < H && gc >= 0 && gc < W)
        v = xb[((size_t)ci * H + gr) * W + gc];
      Xs[t] = v;
    }
    __syncthreads();
    for (int i = 0; i < 7; ++i) {
      const float* xr = &Xs[(tr + i) * 520 + lane];
      float v[8][7];
#pragma unroll
      for (int p = 0; p < 8; ++p)
#pragma unroll
        for (int k = 0; k < 7; ++k) v[p][k] = xr[p * 64 + k];
#pragma unroll
      for (int j = 0; j < 8; ++j) {
        const float* wr = &wsh[(j * 3 + ci) * 49 + i * 7];
        float w0 = wr[0], w1 = wr[1], w2 = wr[2], w3 = wr[3], w4 = wr[4],
              w5 = wr[5], w6 = wr[6];
#pragma unroll
        for (int p = 0; p < 8; ++p)
          acc[j][p] += v[p][0] * w0 + v[p][1] * w1 + v[p][2] * w2 +
                       v[p][3] * w3 + v[p][4] * w4 + v[p][5] * w5 +
                       v[p][6] * w6;
      }
    }
  }
  int r = r0 + tr;
#pragma unroll
  for (int j = 0; j < 8; ++j) {
    int co = cog * 8 + j;
    float bv = bias[co];
    f16* yr = y + ((size_t)(n * 64 + co) * H + r) * W + lane;
    float s = 0.f, q = 0.f;
#pragma unroll
    for (int p = 0; p < 8; ++p) {
      float o = acc[j][p] + bv;
      yr[p * 64] = __float2half(o);
      s += o;
      q += o * o;
    }
#pragma unroll
    for (int off = 32; off > 0; off >>= 1) {
      s += __shfl_down(s, off, 64);
      q += __shfl_down(q, off, 64);
    }
    if (lane == 0) {
      sred[tr][j] = s;
      qred[tr][j] = q;
    }
  }
  __syncthreads();
  if (tid < 8) {
    float S = sred[0][tid] + sred[1][tid] + sred[2][tid] + sred[3][tid];
    float Q = qred[0][tid] + qred[1][tid] + qred[2][tid] + qred[3][tid];
    atomicAdd(&stats[n * 64 + cog * 8 + tid], S);
    atomicAdd(&stats[1024 + n * 64 + cog * 8 + tid], Q);
  }
}

// ---------------- head: 7x7 conv p3, CI=64 (bf16 in), LDS-tiled + tanh ------
// ci-chunked (2/chunk); f16 weights in LDS. grid (128,1,4).
// LDS: 20.8K (Xs) + 18.8K (wsh) = 39.6 KB.
__global__ __launch_bounds__(256) void conv7_head(
    const bf16* __restrict__ xin, const float* __restrict__ w,
    const float* __restrict__ bias, float* __restrict__ y) {
  const int H = 512, W = 512;
  __shared__ unsigned short Xs[10400];  // [2][10][520] bf16 bits
  __shared__ unsigned short wsh[9408];  // [3][64][49] f16 bits
  int n = blockIdx.z;
  int tid = threadIdx.x;
  int r0 = blockIdx.x * 4;
  int tr = tid >> 6;
  int lane = tid & 63;
  for (int t = tid; t < 9408; t += 256) wsh[t] = f2hu(w[t]);
  const unsigned short* xb =
      (const unsigned short*)xin + (size_t)n * 64 * H * W;
  float acc[3][8];
#pragma unroll
  for (int j = 0; j < 3; ++j) {
    float b = bias[j];
#pragma unroll
    for (int p = 0; p < 8; ++p) acc[j][p] = b;
  }
  for (int cc0 = 0; cc0 < 64; cc0 += 2) {
    __syncthreads();  // protect Xs from prev chunk's readers (+wsh 1st it)
    for (int t = tid; t < 10400; t += 256) {
      int ci = t / 5200;
      int rem = t - ci * 5200;
      int row = rem / 520;
      int col = rem - row * 520;
      int gr = r0 - 3 + row;
      int gc = col - 3;
      unsigned short v = 0;
      if (gr >= 0 && gr < H && gc >= 0 && gc < W)
        v = xb[((size_t)(cc0 + ci) * H + gr) * W + gc];
      Xs[t] = v;
    }
    __syncthreads();
    for (int ci = 0; ci < 2; ++ci)
      for (int i = 0; i < 7; ++i) {
        const unsigned short* xr = &Xs[(ci * 10 + tr + i) * 520 + lane];
        float v[8][7];
#pragma unroll
        for (int p = 0; p < 8; ++p)
#pragma unroll
          for (int k = 0; k < 7; ++k) v[p][k] = bu2f(xr[p * 64 + k]);
#pragma unroll
        for (int j = 0; j < 3; ++j) {
          const unsigned short* wr = &wsh[(j * 64 + cc0 + ci) * 49 + i * 7];
          float w0 = hu2f(wr[0]), w1 = hu2f(wr[1]), w2 = hu2f(wr[2]),
                w3 = hu2f(wr[3]), w4 = hu2f(wr[4]), w5 = hu2f(wr[5]),
                w6 = hu2f(wr[6]);
#pragma unroll
          for (int p = 0; p < 8; ++p)
            acc[j][p] += v[p][0] * w0 + v[p][1] * w1 + v[p][2] * w2 +
                         v[p][3] * w3 + v[p][4] * w4 + v[p][5] * w5 +
                         v[p][6] * w6;
        }
      }
  }
  int r = r0 + tr;
#pragma unroll
  for (int j = 0; j < 3; ++j) {
    float* yr = y + ((size_t)(n * 3 + j) * H + r) * W + lane;
#pragma unroll
    for (int p = 0; p < 8; ++p) yr[p * 64] = tanhf(acc[j][p]);
  }
}

// ---------------- 3x3 s2 p1 conv, tiled 4 px x 4 co ------------------------
// NORM: input v = relu(x*sc[n,ci] + sh[n,ci]) fused from stats (AdaLIN coefs)
template <typename Tin, typename Tout, bool NORM>
__global__ __launch_bounds__(256) void conv3x3s2_tile(
    const Tin* __restrict__ x, const float* __restrict__ w,
    const float* __restrict__ bias, const float* __restrict__ stats,
    Tout* __restrict__ y, int Ci, int Hi, int Wi) {
  int Ho = Hi >> 1, Wo = Wi >> 1;
  int cog = blockIdx.y;
  int Co = gridDim.y * 4;
  int n = blockIdx.z;
  int CG = Wo >> 2;
  int rpb = 256 / CG;
  int tid = threadIdx.x;
  int r = blockIdx.x * rpb + tid / CG;
  int c0 = (tid % CG) * 4;
  const Tin* xb = x + (size_t)n * Ci * Hi * Wi;
  int ir0 = 2 * r - 1;
  float mr0 = (ir0 >= 0) ? 1.f : 0.f;
  int cr0 = max(ir0, 0);
  int icl = 2 * c0 - 1;
  float mcl = (icl >= 0) ? 1.f : 0.f;
  int ccl = max(icl, 0);
  float acc[4][4];
#pragma unroll
  for (int j = 0; j < 4; ++j) {
    float b = bias[cog * 4 + j];
#pragma unroll
    for (int p = 0; p < 4; ++p) acc[j][p] = b;
  }
  for (int ci = 0; ci < Ci; ++ci) {
    const Tin* xc = xb + (size_t)ci * Hi * Wi;
    float sc = 1.f, sh = 0.f;
    if (NORM) {
      sc = stats[2048 + n * Ci + ci];
      sh = stats[3072 + n * Ci + ci];
    }
    float v[3][9];
#pragma unroll
    for (int i = 0; i < 3; ++i) {
      int rr = (i == 0) ? cr0 : (2 * r - 1 + i);
      float mi = (i == 0) ? mr0 : 1.f;
      const Tin* xr = xc + (size_t)rr * Wi;
      float t[9];
      t[0] = (float)xr[ccl];
      float4 a = ld4(xr + 2 * c0);
      float4 b4 = ld4(xr + 2 * c0 + 4);
      t[1] = a.x;
      t[2] = a.y;
      t[3] = a.z;
      t[4] = a.w;
      t[5] = b4.x;
      t[6] = b4.y;
      t[7] = b4.z;
      t[8] = b4.w;
      if (NORM) {
#pragma unroll
        for (int k = 0; k < 9; ++k) t[k] = fmaxf(fmaf(t[k], sc, sh), 0.f);
      }
      v[i][0] = t[0] * (mcl * mi);
#pragma unroll
      for (int k = 1; k < 9; ++k) v[i][k] = t[k] * mi;
    }
#pragma unroll
    for (int j = 0; j < 4; ++j) {
      const float* wc = w + ((size_t)(cog * 4 + j) * Ci + ci) * 9;
#pragma unroll
      for (int p = 0; p < 4; ++p) {
        acc[j][p] += v[0][2 * p] * wc[0] + v[0][2 * p + 1] * wc[1] +
                     v[0][2 * p + 2] * wc[2] + v[1][2 * p] * wc[3] +
                     v[1][2 * p + 1] * wc[4] + v[1][2 * p + 2] * wc[5] +
                     v[2][2 * p] * wc[6] + v[2][2 * p + 1] * wc[7] +
                     v[2][2 * p + 2] * wc[8];
      }
    }
  }
#pragma unroll
  for (int j = 0; j < 4; ++j) {
    float4 o = {acc[j][0], acc[j][1], acc[j][2], acc[j][3]};
    st4(y + ((size_t)(n * Co + cog * 4 + j) * Ho + r) * Wo + c0, o);
  }
}

// ---------------- 1x1 conv, tiled 4 px x 4 co, fp32 -------------------------
__global__ __launch_bounds__(256) void conv1x1_tile(
    const float* __restrict__ x, const float* __restrict__ w,
    const float* __restrict__ bias, float* __restrict__ y, int Ci, int HW) {
  int cog = blockIdx.y;
  int Co = gridDim.y * 4;
  int n = blockIdx.z;
  int p0 = (blockIdx.x * 256 + threadIdx.x) * 4;
  const float* xb = x + (size_t)n * Ci * HW + p0;
  float acc[4][4];
#pragma unroll
  for (int j = 0; j < 4; ++j) {
    float b = bias[cog * 4 + j];
#pragma unroll
    for (int p = 0; p < 4; ++p) acc[j][p] = b;
  }
  for (int ci = 0; ci < Ci; ++ci) {
    float4 xv = *(const float4*)(xb + (size_t)ci * HW);
#pragma unroll
    for (int j = 0; j < 4; ++j) {
      float wv = w[(size_t)(cog * 4 + j) * Ci + ci];
      acc[j][0] += xv.x * wv;
      acc[j][1] += xv.y * wv;
      acc[j][2] += xv.z * wv;
      acc[j][3] += xv.w * wv;
    }
  }
#pragma unroll
  for (int j = 0; j < 4; ++j) {
    float4 o = {acc[j][0], acc[j][1], acc[j][2], acc[j][3]};
    *(float4*)(y + (size_t)(n * Co + cog * 4 + j) * HW + p0) = o;
  }
}

// ---------------- ConvTranspose2d k3 s2 p1 op1, tiled 2x2 quad x 4 co -------
template <typename Tin, typename Tout>
__global__ __launch_bounds__(256) void convt3x3_tile(
    const Tin* __restrict__ x, const float* __restrict__ w,
    const float* __restrict__ bias, Tout* __restrict__ y, int Ci, int Hi,
    int Wi) {
  int Ho = Hi * 2, Wo = Wi * 2;
  int cog = blockIdx.y;
  int Co = gridDim.y * 4;
  int n = blockIdx.z;
  int q = blockIdx.x * 256 + threadIdx.x;
  int yq = q / Wi, xq = q % Wi;
  const Tin* xb = x + (size_t)n * Ci * Hi * Wi;
  float mx = (xq + 1 < Wi) ? 1.f : 0.f;
  int x1 = min(xq + 1, Wi - 1);
  float my = (yq + 1 < Hi) ? 1.f : 0.f;
  int y1 = min(yq + 1, Hi - 1);
  float mxy = mx * my;
  float acc[4][4];
#pragma unroll
  for (int j = 0; j < 4; ++j) {
    float b = bias[cog * 4 + j];
#pragma unroll
    for (int p = 0; p < 4; ++p) acc[j][p] = b;
  }
  for (int ci = 0; ci < Ci; ++ci) {
    const Tin* xc = xb + (size_t)ci * Hi * Wi;
    float a = (float)xc[(size_t)yq * Wi + xq];
    float bv = (float)xc[(size_t)yq * Wi + x1] * mx;
    float c = (float)xc[(size_t)y1 * Wi + xq] * my;
    float d = (float)xc[(size_t)y1 * Wi + x1] * mxy;
#pragma unroll
    for (int j = 0; j < 4; ++j) {
      const float* wc = w + ((size_t)ci * Co + cog * 4 + j) * 9;
      acc[j][0] += a * wc[4];
      acc[j][1] += bv * wc[3] + a * wc[5];
      acc[j][2] += c * wc[1] + a * wc[7];
      acc[j][3] += d * wc[0] + c * wc[2] + bv * wc[6] + a * wc[8];
    }
  }
#pragma unroll
  for (int j = 0; j < 4; ++j) {
    size_t base = ((size_t)(n * Co + cog * 4 + j) * Ho + 2 * yq) * Wo + 2 * xq;
    stv(y, base, acc[j][0]);
    stv(y, base + 1, acc[j][1]);
    stv(y, base + Wo, acc[j][2]);
    stv(y, base + Wo + 1, acc[j][3]);
  }
}

// ---------------- per-(n,c) sum / sumsq reduction ---------------------------
template <typename Tin>
__global__ __launch_bounds__(256) void reduce_nc_kernel(
    const Tin* __restrict__ x, float* __restrict__ stats, int HW) {
  int b = blockIdx.x;
  const Tin* p = x + (size_t)b * HW;
  float s = 0.f, q = 0.f;
  for (int i = threadIdx.x; i < HW; i += 256) {
    float v = (float)p[i];
    s += v;
    q += v * v;
  }
  __shared__ float ss[256], qq[256];
  ss[threadIdx.x] = s;
  qq[threadIdx.x] = q;
  __syncthreads();
  for (int off = 128; off > 0; off >>= 1) {
    if (threadIdx.x < off) {
      ss[threadIdx.x] += ss[threadIdx.x + off];
      qq[threadIdx.x] += qq[threadIdx.x + off];
    }
    __syncthreads();
  }
  if (threadIdx.x == 0) {
    stats[b] = ss[0];
    stats[1024 + b] = qq[0];
  }
}

// ---------------- AdaLIN coefficients ---------------------------------------
__global__ void adalin_coef_kernel(float* __restrict__ stats,
                                   const float* __restrict__ rho,
                                   const float* __restrict__ gam,
                                   const float* __restrict__ bet, int N, int C,
                                   float invHW) {
  int i = blockIdx.x * blockDim.x + threadIdx.x;
  if (i >= N * C) return;
  int c = i % C;
  const float* sums = stats;
  const float* sqs = stats + 1024;
  float im = sums[i] * invHW;
  float iv = sqs[i] * invHW - im * im;
  float lsum = 0.f, lsq = 0.f;
  for (int n = 0; n < N; ++n) {
    lsum += sums[n * C + c];
    lsq += sqs[n * C + c];
  }
  float lm = lsum * invHW / N;
  float lv = lsq * invHW / N - lm * lm;
  float r = rho[c];
  float mean = r * im + (1.f - r) * lm;
  float var = fmaxf(r * iv + (1.f - r) * lv, 0.f);
  float sc = gam[c] / sqrtf(var + EPSN);
  stats[2048 + i] = sc;
  stats[3072 + i] = bet[c] - mean * sc;
}

// ---------------- InstanceNorm coefficients ---------------------------------
__global__ void inorm_coef_kernel(float* __restrict__ stats, int NC,
                                  float invHW) {
  int i = blockIdx.x * blockDim.x + threadIdx.x;
  if (i >= NC) return;
  float im = stats[i] * invHW;
  float iv = fmaxf(stats[1024 + i] * invHW - im * im, 0.f);
  float sc = 1.f / sqrtf(iv + EPSN);
  stats[2048 + i] = sc;
  stats[3072 + i] = -im * sc;
}

// ---------------- x = (relu?)(x*scale[nc] + shift[nc])  (in-place) ----------
template <typename T>
__global__ __launch_bounds__(256) void scale_shift_kernel(
    T* __restrict__ x, const float* __restrict__ stats, int HW, size_t total,
    int relu) {
  size_t i = (size_t)blockIdx.x * 256 + threadIdx.x;
  if (i >= total) return;
  int nc = (int)(i / (size_t)HW);
  float v = (float)x[i] * stats[2048 + nc] + stats[3072 + nc];
  if (relu) v = fmaxf(v, 0.f);
  stv(x, i, v);
}

// ---------------- dst = relu(dst + a)  (fp32) -------------------------------
__global__ __launch_bounds__(256) void add_relu_kernel(
    float* __restrict__ dst, const float* __restrict__ a, size_t total) {
  size_t i = (size_t)blockIdx.x * 256 + threadIdx.x;
  if (i >= total) return;
  dst[i] = fmaxf(dst[i] + a[i], 0.f);
}

// ---------------- windowed attention (all fp32) -----------------------------
__global__ __launch_bounds__(256) void win_attn_kernel(
    const float* __restrict__ f, const float* __restrict__ g,
    const float* __restrict__ h, float* __restrict__ out) {
  const int H = 128;
  int j = blockIdx.x;
  int i = blockIdx.y;
  int b = blockIdx.z;
  __shared__ float fs[32 * 64];
  __shared__ float gs[32 * 64];
  __shared__ float att[16 * 64];
  int t = threadIdx.x;
  for (int idx = t; idx < 32 * 64; idx += 256) {
    int c = idx >> 6, k = idx & 63;
    int hr = i * 4 + (k >> 3), wc = j * 4 + (k & 7);
    float fv = 0.f, gv = 0.f;
    if (hr < H && wc < H) {
      size_t o = ((size_t)(b * 32 + c) * H + hr) * H + wc;
      fv = f[o];
      gv = g[o];
    }
    fs[idx] = fv;
    gs[idx] = gv;
  }
  __syncthreads();
  for (int idx = t; idx < 1024; idx += 256) {
    int q = idx >> 6, k = idx & 63;
    int qi = (q >> 2) * 8 + (q & 3);
    int hr = i * 4 + (k >> 3), wc = j * 4 + (k & 7);
    float s;
    if (hr < H && wc < H) {
      s = 0.f;
      for (int c = 0; c < 32; ++c) s += fs[c * 64 + qi] * gs[c * 64 + k];
    } else {
      s = -1e30f;
    }
    att[idx] = s;
  }
  __syncthreads();
  if (t < 16) {
    float m = -1e30f;
    for (int k = 0; k < 64; ++k) m = fmaxf(m, att[t * 64 + k]);
    float d = 0.f;
    for (int k = 0; k < 64; ++k) {
      float e = expf(att[t * 64 + k] - m);
      att[t * 64 + k] = e;
      d += e;
    }
    float inv = 1.f / d;
    for (int k = 0; k < 64; ++k) att[t * 64 + k] *= inv;
  }
  __syncthreads();
  int c = t;
  float accs[16];
  for (int q = 0; q < 16; ++q) accs[q] = 0.f;
  const float* hb = h + (size_t)(b * 256 + c) * H * H;
  for (int k = 0; k < 64; ++k) {
    int hr = i * 4 + (k >> 3), wc = j * 4 + (k & 7);
    if (hr >= H || wc >= H) continue;
    float hv = hb[hr * H + wc];
    for (int q = 0; q < 16; ++q) accs[q] += hv * att[q * 64 + k];
  }
  for (int q = 0; q < 16; ++q) {
    int oh = i * 4 + (q >> 2), ow = j * 4 + (q & 3);
    out[((size_t)(b * 256 + c) * H + oh) * H + ow] = accs[q];
  }
}

// ============================================================================
extern "C" void kernel_launch(void* const* d_in, const int* in_sizes, int n_in,
                              void* d_out, int out_size, void* d_ws,
                              size_t ws_size, hipStream_t stream) {
  const float* x = (const float*)d_in[0];
  const float* w_e1 = (const float*)d_in[1];
  const float* b_e1 = (const float*)d_in[2];
  const float* rho1 = (const float*)d_in[3];
  const float* gam1 = (const float*)d_in[4];
  const float* bet1 = (const float*)d_in[5];
  const float* w_e2 = (const float*)d_in[6];
  const float* b_e2 = (const float*)d_in[7];
  const float* rho2 = (const float*)d_in[8];
  const float* gam2 = (const float*)d_in[9];
  const float* bet2 = (const float*)d_in[10];
  const float* w_e3 = (const float*)d_in[11];
  const float* b_e3 = (const float*)d_in[12];
  const float* rho3 = (const float*)d_in[13];
  const float* gam3 = (const float*)d_in[14];
  const float* bet3 = (const float*)d_in[15];
  const float* rw1 = (const float*)d_in[16];
  const float* rb1 = (const float*)d_in[17];
  const float* rw2 = (const float*)d_in[18];
  const float* rb2 = (const float*)d_in[19];
  const float* w_f = (const float*)d_in[20];
  const float* b_f = (const float*)d_in[21];
  const float* w_g = (const float*)d_in[22];
  const float* b_g = (const float*)d_in[23];
  const float* w_h = (const float*)d_in[24];
  const float* b_h = (const float*)d_in[25];
  const float* w_d1 = (const float*)d_in[26];
  const float* b_d1 = (const float*)d_in[27];
  const float* rho4 = (const float*)d_in[28];
  const float* gam4 = (const float*)d_in[29];
  const float* bet4 = (const float*)d_in[30];
  const float* w_d2 = (const float*)d_in[31];
  const float* b_d2 = (const float*)d_in[32];
  const float* rho5 = (const float*)d_in[33];
  const float* gam5 = (const float*)d_in[34];
  const float* bet5 = (const float*)d_in[35];
  const float* w_d3 = (const float*)d_in[36];
  const float* b_d3 = (const float*)d_in[37];

  // ws layout (192 MiB):
  // E1H f16 raw e1 [0,128MiB) (dead after e2)
  // B2H f16 raw e2 [128,192) (dead after e3; later Bb2 bf16 d1 out)
  // Cc fp32 [0,64), D fp32 [64,128), E fp32 [128,192) (residual stage)
  // F1/F2 fp32 [64,80) (attention f/g); A2 bf16 [0,128) (d2 out)
  char* wsb = (char*)d_ws;
  f16* E1H = (f16*)wsb;
  float* Cc = (float*)wsb;
  float* D = (float*)(wsb + 67108864);
  float* E = (float*)(wsb + 134217728);
  float* F1 = (float*)(wsb + 67108864);
  float* F2 = (float*)(wsb + 75497472);
  f16* B2H = (f16*)(wsb + 134217728);
  bf16* Bb2 = (bf16*)(wsb + 134217728);
  bf16* A2 = (bf16*)wsb;

  float* out_img = (float*)d_out;
  float* out_attn = out_img + 3145728;
  // 16 KiB stats scratch at head of img region; fully overwritten by head conv
  float* stats = (float*)d_out;
  // bf16 hi+lo residual weights scratch in the (not yet written) out_attn
  // region; fully consumed before win_attn_kernel writes out_attn.
  unsigned short* wbres = (unsigned short*)((char*)d_out + 12582912);

  dim3 blk(256);

  // ---- convert residual weights to bf16 hi+lo [tap][co][ci] (once) ----
  convert_w_kernel<<<18432, blk, 0, stream>>>(rw1, rw2, wbres);

  // ---- e1: 7x7 conv (LDS-tiled) -> raw f16 + stats ----
  zero_stats_kernel<<<1, 256, 0, stream>>>(stats);
  conv7_e1<<<dim3(128, 8, 4), blk, 0, stream>>>(x, w_e1, b_e1, stats, E1H);
  adalin_coef_kernel<<<1, 256, 0, stream>>>(stats, rho1, gam1, bet1, 4, 64,
                                            1.f / 262144.f);
  // ---- e2: 3x3 s2 conv with fused e1-norm+relu -> raw f16 ----
  conv3x3s2_tile<f16, f16, true><<<dim3(64, 32, 4), blk, 0, stream>>>(
      E1H, w_e2, b_e2, stats, B2H, 64, 512, 512);
  reduce_nc_kernel<f16><<<512, blk, 0, stream>>>(B2H, stats, 65536);
  adalin_coef_kernel<<<2, 256, 0, stream>>>(stats, rho2, gam2, bet2, 4, 128,
                                            1.f / 65536.f);
  // ---- e3: 3x3 s2 conv with fused e2-norm+relu -> fp32, then AdaLIN ----
  conv3x3s2_tile<f16, float, true><<<dim3(16, 64, 4), blk, 0, stream>>>(
      B2H, w_e3, b_e3, stats, Cc, 128, 256, 256);
  reduce_nc_kernel<float><<<1024, blk, 0, stream>>>(Cc, stats, 16384);
  adalin_coef_kernel<<<4, 256, 0, stream>>>(stats, rho3, gam3, bet3, 4, 256,
                                            1.f / 16384.f);
  scale_shift_kernel<float><<<65536, blk, 0, stream>>>(Cc, stats, 16384,
                                                       (size_t)16777216, 1);
  // ---- 4 residual blocks (bf16x3 MFMA convs) ----
  for (int r = 0; r < 4; ++r) {
    const float* rb1p = rb1 + (size_t)r * 256;
    const float* rb2p = rb2 + (size_t)r * 256;
    const unsigned short* w1h = wbres + (size_t)(r * 2) * 589824;
    const unsigned short* w1l = w1h + 4718592;
    const unsigned short* w2h = wbres + (size_t)(r * 2 + 1) * 589824;
    const unsigned short* w2l = w2h + 4718592;
    conv3x3s1_mfma<<<dim3(128, 2, 4), blk, 0, stream>>>(Cc, w1h, w1l, rb1p, D);
    reduce_nc_kernel<float><<<1024, blk, 0, stream>>>(D, stats, 16384);
    inorm_coef_kernel<<<4, 256, 0, stream>>>(stats, 1024, 1.f / 16384.f);
    scale_shift_kernel<float><<<65536, blk, 0, stream>>>(D, stats, 16384,
                                                         (size_t)16777216, 1);
    conv3x3s1_mfma<<<dim3(128, 2, 4), blk, 0, stream>>>(D, w2h, w2l, rb2p, E);
    reduce_nc_kernel<float><<<1024, blk, 0, stream>>>(E, stats, 16384);
    inorm_coef_kernel<<<4, 256, 0, stream>>>(stats, 1024, 1.f / 16384.f);
    scale_shift_kernel<float><<<65536, blk, 0, stream>>>(E, stats, 16384,
                                                         (size_t)16777216, 0);
    add_relu_kernel<<<65536, blk, 0, stream>>>(Cc, E, (size_t)16777216);
  }
  // ---- attention: 1x1 convs f/g/h + windowed attention ----
  conv1x1_tile<<<dim3(16, 8, 4), blk, 0, stream>>>(Cc, w_f, b_f, F1, 256,
                                                   16384);
  conv1x1_tile<<<dim3(16, 8, 4), blk, 0, stream>>>(Cc, w_g, b_g, F2, 256,
                                                   16384);
  conv1x1_tile<<<dim3(16, 64, 4), blk, 0, stream>>>(Cc, w_h, b_h, E, 256,
                                                    16384);
  win_attn_kernel<<<dim3(32, 32, 4), blk, 0, stream>>>(F1, F2, E, out_attn);
  // ---- d1: convT 256->128, AdaLIN, relu (bf16 out) ----
  convt3x3_tile<float, bf16><<<dim3(64, 32, 4), blk, 0, stream>>>(
      Cc, w_d1, b_d1, Bb2, 256, 128, 128);
  reduce_nc_kernel<bf16><<<512, blk, 0, stream>>>(Bb2, stats, 65536);
  adalin_coef_kernel<<<2, 256, 0, stream>>>(stats, rho4, gam4, bet4, 4, 128,
                                            1.f / 65536.f);
  scale_shift_kernel<bf16><<<131072, blk, 0, stream>>>(Bb2, stats, 65536,
                                                       (size_t)33554432, 1);
  // ---- d2: convT 128->64, AdaLIN, relu (bf16) ----
  convt3x3_tile<bf16, bf16><<<dim3(256, 16, 4), blk, 0, stream>>>(
      Bb2, w_d2, b_d2, A2, 128, 256, 256);
  reduce_nc_kernel<bf16><<<256, blk, 0, stream>>>(A2, stats, 262144);
  adalin_coef_kernel<<<1, 256, 0, stream>>>(stats, rho5, gam5, bet5, 4, 64,
                                            1.f / 262144.f);
  scale_shift_kernel<bf16><<<262144, blk, 0, stream>>>(A2, stats, 262144,
                                                       (size_t)67108864, 1);
  // ---- head: 7x7 conv (LDS-tiled) + tanh -> fp32 img ----
  conv7_head<<<dim3(128, 1, 4), blk, 0, stream>>>(A2, w_d3, b_d3, out_img);
}